// Round 1
// baseline (2524.750 us; speedup 1.0000x reference)
//
#include <hip/hip_runtime.h>
#include <math.h>

#define Bb 256
#define Ss 512
#define Tt 20
#define Ee 25
#define Hh 128
#define SKIPn 64
#define H4n 512
#define BSn (Bb*Ss)
#define EROWS 16

__device__ __forceinline__ float sigmoid_f(float x) {
    return 1.0f / (1.0f + __expf(-x));
}
__device__ __forceinline__ float tanh_f(float x) {
    float a = fabsf(x);
    float e = __expf(-2.0f * a);
    float r = (1.0f - e) / (1.0f + e);
    return copysignf(r, x);
}

// ---------------- Kernel 1: embedding mean-pool + step mask ----------------
__global__ void pool_kernel(const int* __restrict__ tags,
                            const float* __restrict__ table,
                            float* __restrict__ gru, float* __restrict__ maskf) {
    int group = blockIdx.x * 8 + (threadIdx.x >> 5);
    int lane = threadIdx.x & 31;
    if (group >= BSn) return;
    const int* tg = tags + (size_t)group * Tt;
    float acc = 0.0f;
    int cnt = 0;
    int first = tg[0];
#pragma unroll
    for (int t = 0; t < Tt; t++) {
        int tag = tg[t];
        if (tag != 0) {
            cnt++;
            if (lane < Ee) acc += table[(size_t)tag * Ee + lane];
        }
    }
    float scale = 1.0f / (float)(cnt > 0 ? cnt : 1);
    if (lane < Ee) gru[(size_t)group * Ee + lane] = acc * scale;
    if (lane == 0) maskf[group] = (first != 0) ? 1.0f : 0.0f;
}

// ---------------- Kernel 2: bidirectional LSTM scan ----------------
// One block per batch element. 512 threads; thread j owns output column j.
// R column (128) + Sk column (64) in registers; K (25x512, padded to 28) in LDS.
// Waves 6/7 prefetch x/s one step ahead; threads <128 do the gate math.
__device__ __forceinline__ void lstm_phase(
    int b, int dir,
    const float* __restrict__ gru, const float* __restrict__ skips,
    const float* __restrict__ maskf,
    const float* __restrict__ Kw, const float* __restrict__ Rw,
    const float* __restrict__ Skw, const float* __restrict__ bw,
    float* __restrict__ hs, float* __restrict__ hfwd,
    float* K_lds, float* hbuf, float* zbuf, float* xbuf, float* sbuf)
{
    const int tid = threadIdx.x;

    // Stage K into LDS, zero-padded to 28 rows (so xbuf pad cols hit 0*0).
    for (int idx = tid; idx < 28 * H4n; idx += 512)
        K_lds[idx] = (idx < Ee * H4n) ? Kw[idx] : 0.0f;

    // Per-thread weight columns in registers.
    float rc[Hh];
#pragma unroll
    for (int k = 0; k < Hh; k++) rc[k] = Rw[k * H4n + tid];
    float skc[SKIPn];
#pragma unroll
    for (int k = 0; k < SKIPn; k++) skc[k] = Skw[k * H4n + tid];
    float bias = bw[tid];

    if (tid < Hh) hbuf[tid] = 0.0f;
    if (tid >= 384 && tid < 416) {
        int lane = tid - 384;
        if (lane >= Ee) xbuf[lane] = 0.0f;   // zero pad cols 25..31
    }
    float c = 0.0f, hp = 0.0f;

    // Prefetch step 0 inputs into registers.
    float xr = 0.0f, sr = 0.0f;
    int t0 = dir ? (Ss - 1) : 0;
    if (tid >= 384 && tid < 416) {
        int lane = tid - 384;
        if (lane < Ee) xr = gru[((size_t)b * Ss + t0) * Ee + lane];
    } else if (tid >= 448) {
        int lane = tid - 448;
        sr = skips[((size_t)b * Ss + t0) * SKIPn + lane];
    }
    __syncthreads();

    int tprev = 0;
    for (int i = 0; i < Ss; i++) {
        int t = dir ? (Ss - 1 - i) : i;
        // ---- A phase: gates for step i-1 (threads<128); stage x/s for step i
        if (tid < Hh) {
            if (i > 0) {
                float zi = zbuf[tid], zf = zbuf[tid + Hh];
                float zg = zbuf[tid + 2 * Hh], zo = zbuf[tid + 3 * Hh];
                float cn = sigmoid_f(zf) * c + sigmoid_f(zi) * tanh_f(zg);
                float hn = sigmoid_f(zo) * tanh_f(cn);
                bool mm = (maskf[(size_t)b * Ss + tprev] != 0.0f);
                c = mm ? cn : c;
                hp = mm ? hn : hp;
                hbuf[tid] = hp;
                hs[((size_t)b * Ss + tprev) * (2 * Hh) + dir * Hh + tid] = hp;
            }
        } else if (tid >= 384 && tid < 416) {
            int lane = tid - 384;
            if (lane < Ee) xbuf[lane] = xr;
            int inext = (i + 1 < Ss) ? (i + 1) : (Ss - 1);
            int tn = dir ? (Ss - 1 - inext) : inext;
            if (lane < Ee) xr = gru[((size_t)b * Ss + tn) * Ee + lane];
        } else if (tid >= 448) {
            int lane = tid - 448;
            sbuf[lane] = sr;
            int inext = (i + 1 < Ss) ? (i + 1) : (Ss - 1);
            int tn = dir ? (Ss - 1 - inext) : inext;
            sr = skips[((size_t)b * Ss + tn) * SKIPn + lane];
        }
        __syncthreads();

        // ---- B phase: z_j for step i
        float z = bias;
        const float4* h4 = (const float4*)hbuf;
#pragma unroll
        for (int k = 0; k < Hh / 4; k++) {
            float4 h = h4[k];
            z += h.x * rc[4 * k] + h.y * rc[4 * k + 1] + h.z * rc[4 * k + 2] + h.w * rc[4 * k + 3];
        }
        const float4* x4 = (const float4*)xbuf;
#pragma unroll
        for (int e = 0; e < 7; e++) {
            float4 xv = x4[e];
            z += xv.x * K_lds[(4 * e) * H4n + tid];
            z += xv.y * K_lds[(4 * e + 1) * H4n + tid];
            z += xv.z * K_lds[(4 * e + 2) * H4n + tid];
            z += xv.w * K_lds[(4 * e + 3) * H4n + tid];
        }
        const float4* s4 = (const float4*)sbuf;
#pragma unroll
        for (int k = 0; k < SKIPn / 4; k++) {
            float4 sv = s4[k];
            z += sv.x * skc[4 * k] + sv.y * skc[4 * k + 1] + sv.z * skc[4 * k + 2] + sv.w * skc[4 * k + 3];
        }
        zbuf[tid] = z;
        tprev = t;
        __syncthreads();
    }
    // Final gates for last step.
    if (tid < Hh) {
        float zi = zbuf[tid], zf = zbuf[tid + Hh];
        float zg = zbuf[tid + 2 * Hh], zo = zbuf[tid + 3 * Hh];
        float cn = sigmoid_f(zf) * c + sigmoid_f(zi) * tanh_f(zg);
        float hn = sigmoid_f(zo) * tanh_f(cn);
        bool mm = (maskf[(size_t)b * Ss + tprev] != 0.0f);
        c = mm ? cn : c;
        hp = mm ? hn : hp;
        hs[((size_t)b * Ss + tprev) * (2 * Hh) + dir * Hh + tid] = hp;
        if (dir == 0) hfwd[(size_t)b * Hh + tid] = hp;
    }
    __syncthreads();
}

__global__ void __launch_bounds__(512, 2)
scan_kernel(const float* __restrict__ gru, const float* __restrict__ skips,
            const float* __restrict__ maskf,
            const float* __restrict__ Kf, const float* __restrict__ Rf,
            const float* __restrict__ Skf, const float* __restrict__ bf,
            const float* __restrict__ Kb, const float* __restrict__ Rb,
            const float* __restrict__ Skb, const float* __restrict__ bb,
            float* __restrict__ hs, float* __restrict__ hfwd)
{
    __shared__ __align__(16) float K_lds[28 * H4n];
    __shared__ __align__(16) float hbuf[Hh];
    __shared__ __align__(16) float zbuf[H4n];
    __shared__ __align__(16) float xbuf[32];
    __shared__ __align__(16) float sbuf[SKIPn];
    int b = blockIdx.x;
    lstm_phase(b, 0, gru, skips, maskf, Kf, Rf, Skf, bf, hs, hfwd, K_lds, hbuf, zbuf, xbuf, sbuf);
    lstm_phase(b, 1, gru, skips, maskf, Kb, Rb, Skb, bb, hs, hfwd, K_lds, hbuf, zbuf, xbuf, sbuf);
}

// ---------------- Kernel 3: qtot = h_fwd @ Wq + bq + bk ----------------
__global__ void q_kernel(const float* __restrict__ hfwd, const float* __restrict__ Wq,
                         const float* __restrict__ bq, const float* __restrict__ bk,
                         float* __restrict__ qtot) {
    __shared__ float hl[Hh];
    int b = blockIdx.x, j = threadIdx.x;
    hl[j] = hfwd[(size_t)b * Hh + j];
    __syncthreads();
    float q = bq[j] + bk[j];
#pragma unroll
    for (int k = 0; k < Hh; k++) q += hl[k] * Wq[k * Hh + j];
    qtot[(size_t)b * Hh + j] = q;
}

// ---------------- Kernel 4: energy = tanh(out@Wk + qtot) @ We ----------------
__global__ void __launch_bounds__(256, 2)
energy_kernel(const float* __restrict__ hs, const float* __restrict__ qtot,
              const float* __restrict__ Wk, const float* __restrict__ We,
              float* __restrict__ energy)
{
    __shared__ __align__(16) float olds[EROWS][2 * Hh];
    __shared__ __align__(16) float keybuf[EROWS][Hh];
    __shared__ float red[EROWS][8];
    int b = blockIdx.x / (Ss / EROWS);
    int s0 = (blockIdx.x % (Ss / EROWS)) * EROWS;
    int tid = threadIdx.x;

    const float4* src4 = (const float4*)(hs + ((size_t)b * Ss + s0) * (2 * Hh));
    float4* dst4 = (float4*)&olds[0][0];
    for (int i = tid; i < EROWS * 2 * Hh / 4; i += 256) dst4[i] = src4[i];
    __syncthreads();

    int j = tid & 127;
    int half = tid >> 7;
    float wk[Hh];
#pragma unroll
    for (int k = 0; k < Hh; k++) wk[k] = Wk[(half * Hh + k) * Hh + j];
    float qj = qtot[(size_t)b * Hh + j];
    float acc[EROWS];
#pragma unroll
    for (int r = 0; r < EROWS; r++) acc[r] = (half == 0) ? qj : 0.0f;

#pragma unroll
    for (int r = 0; r < EROWS; r++) {
        const float4* o4 = (const float4*)&olds[r][half * Hh];
#pragma unroll
        for (int k = 0; k < Hh / 4; k++) {
            float4 o = o4[k];
            acc[r] += o.x * wk[4 * k] + o.y * wk[4 * k + 1] + o.z * wk[4 * k + 2] + o.w * wk[4 * k + 3];
        }
    }
    if (half == 1) {
#pragma unroll
        for (int r = 0; r < EROWS; r++) keybuf[r][j] = acc[r];
    }
    __syncthreads();
    if (half == 0) {
        float wej = We[j];
#pragma unroll
        for (int r = 0; r < EROWS; r++) {
            float key = acc[r] + keybuf[r][j];
            keybuf[r][j] = tanh_f(key) * wej;
        }
    }
    __syncthreads();
    if (tid < EROWS * 8) {
        int r = tid >> 3, l = tid & 7;
        float s = 0.0f;
#pragma unroll
        for (int i2 = 0; i2 < 16; i2++) s += keybuf[r][l * 16 + i2];
        red[r][l] = s;
    }
    __syncthreads();
    if (tid < EROWS) {
        float e = 0.0f;
#pragma unroll
        for (int l = 0; l < 8; l++) e += red[tid][l];
        energy[(size_t)b * Ss + s0 + tid] = e;
    }
}

// ---------------- Kernel 5: masked softmax over S + weighted context ----------------
__global__ void __launch_bounds__(256)
ctx_kernel(const float* __restrict__ energy, const float* __restrict__ maskf,
           const float* __restrict__ hs, float* __restrict__ outp)
{
    __shared__ __align__(16) float w[Ss];
    __shared__ float redm[4], reds[4];
    int b = blockIdx.x, tid = threadIdx.x;

    float e0 = energy[(size_t)b * Ss + tid];
    float e1 = energy[(size_t)b * Ss + tid + 256];
    float m0 = maskf[(size_t)b * Ss + tid];
    float m1 = maskf[(size_t)b * Ss + tid + 256];
    e0 += (1.0f - m0) * -1e9f;
    e1 += (1.0f - m1) * -1e9f;

    float mx = fmaxf(e0, e1);
#pragma unroll
    for (int off = 32; off > 0; off >>= 1) mx = fmaxf(mx, __shfl_down(mx, off));
    if ((tid & 63) == 0) redm[tid >> 6] = mx;
    __syncthreads();
    mx = fmaxf(fmaxf(redm[0], redm[1]), fmaxf(redm[2], redm[3]));

    float p0 = __expf(e0 - mx), p1 = __expf(e1 - mx);
    float sm = p0 + p1;
#pragma unroll
    for (int off = 32; off > 0; off >>= 1) sm += __shfl_down(sm, off);
    if ((tid & 63) == 0) reds[tid >> 6] = sm;
    __syncthreads();
    sm = reds[0] + reds[1] + reds[2] + reds[3];
    float inv = 1.0f / sm;
    w[tid] = p0 * inv;
    w[tid + 256] = p1 * inv;
    __syncthreads();

    float ctx = 0.0f;
    const float* hsb = hs + (size_t)b * Ss * (2 * Hh) + tid;
    const float4* w4 = (const float4*)w;
#pragma unroll 2
    for (int s4i = 0; s4i < Ss / 4; s4i++) {
        float4 ww = w4[s4i];
        size_t base = (size_t)(s4i * 4) * (2 * Hh);
        ctx += ww.x * hsb[base];
        ctx += ww.y * hsb[base + 256];
        ctx += ww.z * hsb[base + 512];
        ctx += ww.w * hsb[base + 768];
    }
    outp[(size_t)b * (2 * Hh) + tid] = ctx;
}

// ---------------- Launcher ----------------
extern "C" void kernel_launch(void* const* d_in, const int* in_sizes, int n_in,
                              void* d_out, int out_size, void* d_ws, size_t ws_size,
                              hipStream_t stream) {
    const int*   tags  = (const int*)d_in[0];
    const float* skips = (const float*)d_in[1];
    const float* table = (const float*)d_in[2];
    const float* Kf    = (const float*)d_in[3];
    const float* Rf    = (const float*)d_in[4];
    const float* Skf   = (const float*)d_in[5];
    const float* bf    = (const float*)d_in[6];
    const float* Kb    = (const float*)d_in[7];
    const float* Rb    = (const float*)d_in[8];
    const float* Skb   = (const float*)d_in[9];
    const float* bb    = (const float*)d_in[10];
    const float* Wk    = (const float*)d_in[11];
    const float* bk    = (const float*)d_in[12];
    const float* Wq    = (const float*)d_in[13];
    const float* bq    = (const float*)d_in[14];
    const float* We    = (const float*)d_in[15];

    char* ws = (char*)d_ws;
    float* gru    = (float*)ws;  ws += (size_t)BSn * Ee * 4;        // 13.1 MB
    float* maskf  = (float*)ws;  ws += (size_t)BSn * 4;             // 0.5 MB
    float* hs     = (float*)ws;  ws += (size_t)BSn * 2 * Hh * 4;    // 134.2 MB
    float* hfwd   = (float*)ws;  ws += (size_t)Bb * Hh * 4;
    float* qtot   = (float*)ws;  ws += (size_t)Bb * Hh * 4;
    float* energy = (float*)ws;  ws += (size_t)BSn * 4;

    pool_kernel<<<BSn / 8, 256, 0, stream>>>(tags, table, gru, maskf);
    scan_kernel<<<Bb, 512, 0, stream>>>(gru, skips, maskf,
                                        Kf, Rf, Skf, bf,
                                        Kb, Rb, Skb, bb,
                                        hs, hfwd);
    q_kernel<<<Bb, Hh, 0, stream>>>(hfwd, Wq, bq, bk, qtot);
    energy_kernel<<<Bb * (Ss / EROWS), 256, 0, stream>>>(hs, qtot, Wk, We, energy);
    ctx_kernel<<<Bb, 256, 0, stream>>>(energy, maskf, hs, (float*)d_out);
}

// Round 2
// 2254.088 us; speedup vs baseline: 1.1201x; 1.1201x over previous
//
#include <hip/hip_runtime.h>
#include <math.h>

#define Bb 256
#define Ss 512
#define Tt 20
#define Ee 25
#define Hh 128
#define SKIPn 64
#define H4n 512
#define BSn (Bb*Ss)
#define EROWS 16

__device__ __forceinline__ float sigmoid_f(float x) {
    return 1.0f / (1.0f + __expf(-x));
}
__device__ __forceinline__ float tanh_f(float x) {
    float a = fabsf(x);
    float e = __expf(-2.0f * a);
    float r = (1.0f - e) / (1.0f + e);
    return copysignf(r, x);
}
// Broadcast lane k of v to all lanes via SGPR (VALU pipe, avoids LDS pipe).
__device__ __forceinline__ float bcast(float v, int k) {
    return __int_as_float(__builtin_amdgcn_readlane(__float_as_int(v), k));
}

// ---------------- Kernel 1: embedding mean-pool + step mask ----------------
__global__ void pool_kernel(const int* __restrict__ tags,
                            const float* __restrict__ table,
                            float* __restrict__ gru, float* __restrict__ maskf) {
    int group = blockIdx.x * 8 + (threadIdx.x >> 5);
    int lane = threadIdx.x & 31;
    if (group >= BSn) return;
    const int* tg = tags + (size_t)group * Tt;
    float acc = 0.0f;
    int cnt = 0;
    int first = tg[0];
#pragma unroll
    for (int t = 0; t < Tt; t++) {
        int tag = tg[t];
        if (tag != 0) {
            cnt++;
            if (lane < Ee) acc += table[(size_t)tag * Ee + lane];
        }
    }
    float scale = 1.0f / (float)(cnt > 0 ? cnt : 1);
    if (lane < Ee) gru[(size_t)group * Ee + lane] = acc * scale;
    if (lane == 0) maskf[group] = (first != 0) ? 1.0f : 0.0f;
}

// ---------------- Kernel 2: bidirectional LSTM scan ----------------
// Grid = 512 blocks: one per (batch, direction) — fwd/bwd run concurrently.
// 512 threads; thread j owns z-column j with R/K/Sk columns in 217 VGPRs.
// h/x/s broadcast via v_readlane (VALU pipe) — LDS used only for the tiny
// h (128 f) and z (512 f) exchanges. Gate g handled by thread 4g (spreads
// transcendental work across all 8 waves).
__global__ void __launch_bounds__(512)
scan_kernel(const float* __restrict__ gru, const float* __restrict__ skips,
            const float* __restrict__ maskf,
            const float* __restrict__ Kf, const float* __restrict__ Rf,
            const float* __restrict__ Skf, const float* __restrict__ bf,
            const float* __restrict__ Kb, const float* __restrict__ Rb,
            const float* __restrict__ Skb, const float* __restrict__ bb,
            float* __restrict__ hs, float* __restrict__ hfwd)
{
    __shared__ float hbuf[Hh];
    __shared__ float zbuf[H4n];

    const int tid = threadIdx.x;
    const int lane = tid & 63;
    const int b = blockIdx.x & (Bb - 1);
    const int dir = blockIdx.x >> 8;

    const float* Kw = dir ? Kb : Kf;
    const float* Rw = dir ? Rb : Rf;
    const float* Sw = dir ? Skb : Skf;
    const float* bw = dir ? bb : bf;

    // Register-resident weight columns (217 VGPRs).
    float rc[Hh];
#pragma unroll
    for (int k = 0; k < Hh; k++) rc[k] = Rw[k * H4n + tid];
    float kc[Ee];
#pragma unroll
    for (int k = 0; k < Ee; k++) kc[k] = Kw[k * H4n + tid];
    float sc[SKIPn];
#pragma unroll
    for (int k = 0; k < SKIPn; k++) sc[k] = Sw[k * H4n + tid];
    const float bias = bw[tid];

    if ((tid & 3) == 0) hbuf[tid >> 2] = 0.0f;

    // Prefetch step-0 inputs cooperatively: lanes<25 hold x, all 64 hold s.
    int t0 = dir ? (Ss - 1) : 0;
    float xr = (lane < Ee) ? gru[((size_t)b * Ss + t0) * Ee + lane] : 0.0f;
    float sr = skips[((size_t)b * Ss + t0) * SKIPn + lane];

    float c = 0.0f, hp = 0.0f;
    int tprev = 0;
    __syncthreads();

    for (int i = 0; i < Ss; i++) {
        const int t = dir ? (Ss - 1 - i) : i;
        int tn = dir ? (Ss - 2 - i) : (i + 1);
        if (i == Ss - 1) tn = t;  // clamp (value unused)

        const float xcur = xr, scur = sr;
        // Issue next-step prefetch early; latency hidden by the step body.
        xr = (lane < Ee) ? gru[((size_t)b * Ss + tn) * Ee + lane] : 0.0f;
        sr = skips[((size_t)b * Ss + tn) * SKIPn + lane];

        // ---- Phase A: gates of step i-1 (thread 4g owns gate g) ----
        if (i > 0 && (tid & 3) == 0) {
            const int g = tid >> 2;
            float zi = zbuf[g], zf = zbuf[g + Hh];
            float zg = zbuf[g + 2 * Hh], zo = zbuf[g + 3 * Hh];
            float cn = sigmoid_f(zf) * c + sigmoid_f(zi) * tanh_f(zg);
            float hn = sigmoid_f(zo) * tanh_f(cn);
            bool mm = (maskf[(size_t)b * Ss + tprev] != 0.0f);
            c = mm ? cn : c;
            hp = mm ? hn : hp;
            hbuf[g] = hp;
            hs[((size_t)b * Ss + tprev) * (2 * Hh) + dir * Hh + g] = hp;
        }
        __syncthreads();

        // ---- Phase B: z_j for step i ----
        // Cooperative h load: 2 conflict-free ds_read_b32 per wave.
        const float hA = hbuf[lane];
        const float hB = hbuf[64 + lane];

        float z0 = bias, z1 = 0.0f, z2 = 0.0f, z3 = 0.0f;
#pragma unroll
        for (int k = 0; k < 64; k += 4) {
            z0 = fmaf(bcast(hA, k + 0), rc[k + 0], z0);
            z1 = fmaf(bcast(hA, k + 1), rc[k + 1], z1);
            z2 = fmaf(bcast(hA, k + 2), rc[k + 2], z2);
            z3 = fmaf(bcast(hA, k + 3), rc[k + 3], z3);
        }
#pragma unroll
        for (int k = 0; k < 64; k += 4) {
            z0 = fmaf(bcast(hB, k + 0), rc[64 + k + 0], z0);
            z1 = fmaf(bcast(hB, k + 1), rc[64 + k + 1], z1);
            z2 = fmaf(bcast(hB, k + 2), rc[64 + k + 2], z2);
            z3 = fmaf(bcast(hB, k + 3), rc[64 + k + 3], z3);
        }
#pragma unroll
        for (int k = 0; k < 24; k += 4) {
            z0 = fmaf(bcast(xcur, k + 0), kc[k + 0], z0);
            z1 = fmaf(bcast(xcur, k + 1), kc[k + 1], z1);
            z2 = fmaf(bcast(xcur, k + 2), kc[k + 2], z2);
            z3 = fmaf(bcast(xcur, k + 3), kc[k + 3], z3);
        }
        z0 = fmaf(bcast(xcur, 24), kc[24], z0);
#pragma unroll
        for (int k = 0; k < SKIPn; k += 4) {
            z0 = fmaf(bcast(scur, k + 0), sc[k + 0], z0);
            z1 = fmaf(bcast(scur, k + 1), sc[k + 1], z1);
            z2 = fmaf(bcast(scur, k + 2), sc[k + 2], z2);
            z3 = fmaf(bcast(scur, k + 3), sc[k + 3], z3);
        }
        zbuf[tid] = (z0 + z1) + (z2 + z3);
        tprev = t;
        __syncthreads();
    }

    // Final gates for the last step.
    if ((tid & 3) == 0) {
        const int g = tid >> 2;
        float zi = zbuf[g], zf = zbuf[g + Hh];
        float zg = zbuf[g + 2 * Hh], zo = zbuf[g + 3 * Hh];
        float cn = sigmoid_f(zf) * c + sigmoid_f(zi) * tanh_f(zg);
        float hn = sigmoid_f(zo) * tanh_f(cn);
        bool mm = (maskf[(size_t)b * Ss + tprev] != 0.0f);
        c = mm ? cn : c;
        hp = mm ? hn : hp;
        hs[((size_t)b * Ss + tprev) * (2 * Hh) + dir * Hh + g] = hp;
        if (dir == 0) hfwd[(size_t)b * Hh + g] = hp;
    }
}

// ---------------- Kernel 3: qtot = h_fwd @ Wq + bq + bk ----------------
__global__ void q_kernel(const float* __restrict__ hfwd, const float* __restrict__ Wq,
                         const float* __restrict__ bq, const float* __restrict__ bk,
                         float* __restrict__ qtot) {
    __shared__ float hl[Hh];
    int b = blockIdx.x, j = threadIdx.x;
    hl[j] = hfwd[(size_t)b * Hh + j];
    __syncthreads();
    float q = bq[j] + bk[j];
#pragma unroll
    for (int k = 0; k < Hh; k++) q += hl[k] * Wq[k * Hh + j];
    qtot[(size_t)b * Hh + j] = q;
}

// ---------------- Kernel 4: energy = tanh(out@Wk + qtot) @ We ----------------
__global__ void __launch_bounds__(256, 2)
energy_kernel(const float* __restrict__ hs, const float* __restrict__ qtot,
              const float* __restrict__ Wk, const float* __restrict__ We,
              float* __restrict__ energy)
{
    __shared__ __align__(16) float olds[EROWS][2 * Hh];
    __shared__ __align__(16) float keybuf[EROWS][Hh];
    __shared__ float red[EROWS][8];
    int b = blockIdx.x / (Ss / EROWS);
    int s0 = (blockIdx.x % (Ss / EROWS)) * EROWS;
    int tid = threadIdx.x;

    const float4* src4 = (const float4*)(hs + ((size_t)b * Ss + s0) * (2 * Hh));
    float4* dst4 = (float4*)&olds[0][0];
    for (int i = tid; i < EROWS * 2 * Hh / 4; i += 256) dst4[i] = src4[i];
    __syncthreads();

    int j = tid & 127;
    int half = tid >> 7;
    float wk[Hh];
#pragma unroll
    for (int k = 0; k < Hh; k++) wk[k] = Wk[(half * Hh + k) * Hh + j];
    float qj = qtot[(size_t)b * Hh + j];
    float acc[EROWS];
#pragma unroll
    for (int r = 0; r < EROWS; r++) acc[r] = (half == 0) ? qj : 0.0f;

#pragma unroll
    for (int r = 0; r < EROWS; r++) {
        const float4* o4 = (const float4*)&olds[r][half * Hh];
#pragma unroll
        for (int k = 0; k < Hh / 4; k++) {
            float4 o = o4[k];
            acc[r] += o.x * wk[4 * k] + o.y * wk[4 * k + 1] + o.z * wk[4 * k + 2] + o.w * wk[4 * k + 3];
        }
    }
    if (half == 1) {
#pragma unroll
        for (int r = 0; r < EROWS; r++) keybuf[r][j] = acc[r];
    }
    __syncthreads();
    if (half == 0) {
        float wej = We[j];
#pragma unroll
        for (int r = 0; r < EROWS; r++) {
            float key = acc[r] + keybuf[r][j];
            keybuf[r][j] = tanh_f(key) * wej;
        }
    }
    __syncthreads();
    if (tid < EROWS * 8) {
        int r = tid >> 3, l = tid & 7;
        float s = 0.0f;
#pragma unroll
        for (int i2 = 0; i2 < 16; i2++) s += keybuf[r][l * 16 + i2];
        red[r][l] = s;
    }
    __syncthreads();
    if (tid < EROWS) {
        float e = 0.0f;
#pragma unroll
        for (int l = 0; l < 8; l++) e += red[tid][l];
        energy[(size_t)b * Ss + s0 + tid] = e;
    }
}

// ---------------- Kernel 5: masked softmax over S + weighted context ----------------
__global__ void __launch_bounds__(256)
ctx_kernel(const float* __restrict__ energy, const float* __restrict__ maskf,
           const float* __restrict__ hs, float* __restrict__ outp)
{
    __shared__ __align__(16) float w[Ss];
    __shared__ float redm[4], reds[4];
    int b = blockIdx.x, tid = threadIdx.x;

    float e0 = energy[(size_t)b * Ss + tid];
    float e1 = energy[(size_t)b * Ss + tid + 256];
    float m0 = maskf[(size_t)b * Ss + tid];
    float m1 = maskf[(size_t)b * Ss + tid + 256];
    e0 += (1.0f - m0) * -1e9f;
    e1 += (1.0f - m1) * -1e9f;

    float mx = fmaxf(e0, e1);
#pragma unroll
    for (int off = 32; off > 0; off >>= 1) mx = fmaxf(mx, __shfl_down(mx, off));
    if ((tid & 63) == 0) redm[tid >> 6] = mx;
    __syncthreads();
    mx = fmaxf(fmaxf(redm[0], redm[1]), fmaxf(redm[2], redm[3]));

    float p0 = __expf(e0 - mx), p1 = __expf(e1 - mx);
    float sm = p0 + p1;
#pragma unroll
    for (int off = 32; off > 0; off >>= 1) sm += __shfl_down(sm, off);
    if ((tid & 63) == 0) reds[tid >> 6] = sm;
    __syncthreads();
    sm = reds[0] + reds[1] + reds[2] + reds[3];
    float inv = 1.0f / sm;
    w[tid] = p0 * inv;
    w[tid + 256] = p1 * inv;
    __syncthreads();

    float ctx = 0.0f;
    const float* hsb = hs + (size_t)b * Ss * (2 * Hh) + tid;
    const float4* w4 = (const float4*)w;
#pragma unroll 2
    for (int s4i = 0; s4i < Ss / 4; s4i++) {
        float4 ww = w4[s4i];
        size_t base = (size_t)(s4i * 4) * (2 * Hh);
        ctx += ww.x * hsb[base];
        ctx += ww.y * hsb[base + 256];
        ctx += ww.z * hsb[base + 512];
        ctx += ww.w * hsb[base + 768];
    }
    outp[(size_t)b * (2 * Hh) + tid] = ctx;
}

// ---------------- Launcher ----------------
extern "C" void kernel_launch(void* const* d_in, const int* in_sizes, int n_in,
                              void* d_out, int out_size, void* d_ws, size_t ws_size,
                              hipStream_t stream) {
    const int*   tags  = (const int*)d_in[0];
    const float* skips = (const float*)d_in[1];
    const float* table = (const float*)d_in[2];
    const float* Kf    = (const float*)d_in[3];
    const float* Rf    = (const float*)d_in[4];
    const float* Skf   = (const float*)d_in[5];
    const float* bf    = (const float*)d_in[6];
    const float* Kb    = (const float*)d_in[7];
    const float* Rb    = (const float*)d_in[8];
    const float* Skb   = (const float*)d_in[9];
    const float* bb    = (const float*)d_in[10];
    const float* Wk    = (const float*)d_in[11];
    const float* bk    = (const float*)d_in[12];
    const float* Wq    = (const float*)d_in[13];
    const float* bq    = (const float*)d_in[14];
    const float* We    = (const float*)d_in[15];

    char* ws = (char*)d_ws;
    float* gru    = (float*)ws;  ws += (size_t)BSn * Ee * 4;        // 13.1 MB
    float* maskf  = (float*)ws;  ws += (size_t)BSn * 4;             // 0.5 MB
    float* hs     = (float*)ws;  ws += (size_t)BSn * 2 * Hh * 4;    // 134.2 MB
    float* hfwd   = (float*)ws;  ws += (size_t)Bb * Hh * 4;
    float* qtot   = (float*)ws;  ws += (size_t)Bb * Hh * 4;
    float* energy = (float*)ws;  ws += (size_t)BSn * 4;

    pool_kernel<<<BSn / 8, 256, 0, stream>>>(tags, table, gru, maskf);
    scan_kernel<<<2 * Bb, 512, 0, stream>>>(gru, skips, maskf,
                                            Kf, Rf, Skf, bf,
                                            Kb, Rb, Skb, bb,
                                            hs, hfwd);
    q_kernel<<<Bb, Hh, 0, stream>>>(hfwd, Wq, bq, bk, qtot);
    energy_kernel<<<Bb * (Ss / EROWS), 256, 0, stream>>>(hs, qtot, Wk, We, energy);
    ctx_kernel<<<Bb, 256, 0, stream>>>(energy, maskf, hs, (float*)d_out);
}

// Round 3
// 1601.544 us; speedup vs baseline: 1.5764x; 1.4074x over previous
//
#include <hip/hip_runtime.h>
#include <math.h>

#define Bb 256
#define Ss 512
#define Tt 20
#define Ee 25
#define Hh 128
#define SKIPn 64
#define H4n 512
#define BSn (Bb*Ss)
#define EROWS 16
#define MG 16            // batch rows per scan block
#define ZP 20            // Z LDS row pitch in floats (16 + 4 pad)
#define HP 136           // h16 LDS row pitch in halves (128 + 8 pad)

typedef _Float16 f16x8 __attribute__((ext_vector_type(8)));
typedef float f32x4 __attribute__((ext_vector_type(4)));

__device__ __forceinline__ float sigmoid_f(float x) {
    return 1.0f / (1.0f + __expf(-x));
}
__device__ __forceinline__ float tanh_f(float x) {
    float a = fabsf(x);
    float e = __expf(-2.0f * a);
    float r = (1.0f - e) / (1.0f + e);
    return copysignf(r, x);
}

// ---------------- Kernel 1: embedding mean-pool (fp16 out, [t][b][32]) + mask ----------------
__global__ void pool_kernel(const int* __restrict__ tags,
                            const float* __restrict__ table,
                            _Float16* __restrict__ gru16, float* __restrict__ maskf) {
    int group = blockIdx.x * 8 + (threadIdx.x >> 5);
    int lane = threadIdx.x & 31;
    if (group >= BSn) return;
    int b = group >> 9;          // group = b*Ss + t
    int t = group & (Ss - 1);
    const int* tg = tags + (size_t)group * Tt;
    float acc = 0.0f;
    int cnt = 0;
    int first = tg[0];
#pragma unroll
    for (int tt = 0; tt < Tt; tt++) {
        int tag = tg[tt];
        if (tag != 0) {
            cnt++;
            if (lane < Ee) acc += table[(size_t)tag * Ee + lane];
        }
    }
    float scale = 1.0f / (float)(cnt > 0 ? cnt : 1);
    float v = (lane < Ee) ? acc * scale : 0.0f;
    gru16[((size_t)t * Bb + b) * 32 + lane] = (_Float16)v;
    if (lane == 0) maskf[group] = (first != 0) ? 1.0f : 0.0f;
}

// ---------------- Kernel 2: bidirectional LSTM scan via MFMA fp16 ----------------
// Grid = 32 blocks: (dir, 16-batch-group). 512 threads = 8 waves.
// Per step: Z[16,512] = A[16,224] @ W[224,512], A = [x(32 pad) | h(128) | s(64)].
// W held as B-fragments in 112 VGPRs/lane; h feedback via LDS fp16 buffer.
__global__ void __launch_bounds__(512)
__attribute__((amdgpu_waves_per_eu(2, 2)))
scan_kernel(const _Float16* __restrict__ gru16, const float* __restrict__ skips,
            const float* __restrict__ maskf,
            const float* __restrict__ Kf, const float* __restrict__ Rf,
            const float* __restrict__ Skf, const float* __restrict__ bf,
            const float* __restrict__ Kb, const float* __restrict__ Rb,
            const float* __restrict__ Skb, const float* __restrict__ bb,
            float* __restrict__ hs, float* __restrict__ hfwd)
{
    __shared__ __align__(16) float Z[H4n * ZP];        // 40960 B
    __shared__ __align__(16) _Float16 h16[MG * HP];    // 4352 B
    __shared__ __align__(16) float maskbuf[MG];

    const int tid = threadIdx.x;
    const int lane = tid & 63;
    const int w = tid >> 6;          // wave 0..7 (owns cols 64w..64w+63)
    const int l16 = lane & 15;
    const int q = lane >> 4;         // 0..3
    const int bg = blockIdx.x & 15;
    const int dir = blockIdx.x >> 4;
    const int b0 = bg * MG;

    const float* Kw = dir ? Kb : Kf;
    const float* Rw = dir ? Rb : Rf;
    const float* Sw = dir ? Skb : Skf;
    const float* bw = dir ? bb : bf;

    // ---- B-fragments: b[kt][nt][j] = W[32kt + 8q + j][64w + 16nt + l16] (fp16)
    f16x8 bfr[7][4];
#pragma unroll
    for (int kt = 0; kt < 7; kt++) {
#pragma unroll
        for (int nt = 0; nt < 4; nt++) {
            const int n = 64 * w + 16 * nt + l16;
            f16x8 v;
#pragma unroll
            for (int j = 0; j < 8; j++) {
                const int k = 32 * kt + 8 * q + j;
                float x;
                if (k < 32)        x = (k < Ee) ? Kw[k * H4n + n] : 0.0f;
                else if (k < 160)  x = Rw[(k - 32) * H4n + n];
                else               x = Sw[(k - 160) * H4n + n];
                v[j] = (_Float16)x;
            }
            bfr[kt][nt] = v;
        }
    }
    float biasv[4];
#pragma unroll
    for (int nt = 0; nt < 4; nt++) biasv[nt] = bw[64 * w + 16 * nt + l16];

    // zero h feedback buffer
    for (int idx = tid; idx < MG * HP; idx += 512) h16[idx] = (_Float16)0.0f;

    // gate-phase ownership: thread -> (4 batch rows m0..m0+3, column hcol)
    const int hcol = tid & 127;
    const int m0 = (tid >> 7) * 4;
    float creg[4] = {0.f, 0.f, 0.f, 0.f};
    float hreg[4] = {0.f, 0.f, 0.f, 0.f};

    // ---- prefetch step-0 inputs
    int t0 = dir ? (Ss - 1) : 0;
    const float* srow = skips + (size_t)(b0 + l16) * Ss * SKIPn;
    f16x8 xf = *(const f16x8*)(gru16 + ((size_t)t0 * Bb + b0 + l16) * 32 + 8 * q);
    f32x4 sf0 = *(const f32x4*)(srow + (size_t)t0 * SKIPn + 8 * q);
    f32x4 sf1 = *(const f32x4*)(srow + (size_t)t0 * SKIPn + 8 * q + 4);
    f32x4 sf2 = *(const f32x4*)(srow + (size_t)t0 * SKIPn + 32 + 8 * q);
    f32x4 sf3 = *(const f32x4*)(srow + (size_t)t0 * SKIPn + 32 + 8 * q + 4);
    float mreg = (tid < MG) ? maskf[(size_t)(b0 + tid) * Ss + t0] : 0.0f;

    __syncthreads();

#pragma unroll 1
    for (int i = 0; i < Ss; i++) {
        const int tcur = dir ? (Ss - 1 - i) : i;
        const int inx = (i + 1 < Ss) ? i + 1 : i;
        const int tnext = dir ? (Ss - 1 - inx) : inx;

        // current-step A fragments
        const f16x8 ax = xf;
        f16x8 as0, as1;
#pragma unroll
        for (int j = 0; j < 4; j++) {
            as0[j]     = (_Float16)sf0[j];
            as0[j + 4] = (_Float16)sf1[j];
            as1[j]     = (_Float16)sf2[j];
            as1[j + 4] = (_Float16)sf3[j];
        }
        if (tid < MG) maskbuf[tid] = mreg;

        // h fragments from LDS (valid: prev iteration ended with barrier)
        f16x8 ah[4];
#pragma unroll
        for (int kt = 0; kt < 4; kt++)
            ah[kt] = *(const f16x8*)(h16 + l16 * HP + 32 * kt + 8 * q);

        // prefetch next-step inputs (latency hidden under MFMA)
        xf = *(const f16x8*)(gru16 + ((size_t)tnext * Bb + b0 + l16) * 32 + 8 * q);
        sf0 = *(const f32x4*)(srow + (size_t)tnext * SKIPn + 8 * q);
        sf1 = *(const f32x4*)(srow + (size_t)tnext * SKIPn + 8 * q + 4);
        sf2 = *(const f32x4*)(srow + (size_t)tnext * SKIPn + 32 + 8 * q);
        sf3 = *(const f32x4*)(srow + (size_t)tnext * SKIPn + 32 + 8 * q + 4);
        if (tid < MG) mreg = maskf[(size_t)(b0 + tid) * Ss + tnext];

        // ---- MFMA: Z = bias + A @ W
        f32x4 acc[4];
#pragma unroll
        for (int nt = 0; nt < 4; nt++) {
            f32x4 a;
            a[0] = biasv[nt]; a[1] = biasv[nt]; a[2] = biasv[nt]; a[3] = biasv[nt];
            acc[nt] = a;
        }
#pragma unroll
        for (int nt = 0; nt < 4; nt++) {
            acc[nt] = __builtin_amdgcn_mfma_f32_16x16x32_f16(ax,    bfr[0][nt], acc[nt], 0, 0, 0);
            acc[nt] = __builtin_amdgcn_mfma_f32_16x16x32_f16(ah[0], bfr[1][nt], acc[nt], 0, 0, 0);
            acc[nt] = __builtin_amdgcn_mfma_f32_16x16x32_f16(ah[1], bfr[2][nt], acc[nt], 0, 0, 0);
            acc[nt] = __builtin_amdgcn_mfma_f32_16x16x32_f16(ah[2], bfr[3][nt], acc[nt], 0, 0, 0);
            acc[nt] = __builtin_amdgcn_mfma_f32_16x16x32_f16(ah[3], bfr[4][nt], acc[nt], 0, 0, 0);
            acc[nt] = __builtin_amdgcn_mfma_f32_16x16x32_f16(as0,  bfr[5][nt], acc[nt], 0, 0, 0);
            acc[nt] = __builtin_amdgcn_mfma_f32_16x16x32_f16(as1,  bfr[6][nt], acc[nt], 0, 0, 0);
        }
        // write Z' [n][m] (C-layout regs are 4 consecutive rows m)
#pragma unroll
        for (int nt = 0; nt < 4; nt++) {
            const int n = 64 * w + 16 * nt + l16;
            *(f32x4*)(Z + n * ZP + 4 * q) = acc[nt];
        }
        __syncthreads();

        // ---- gates: thread owns (m0..m0+3, hcol)
        const f32x4 zi = *(const f32x4*)(Z + (hcol)*ZP + m0);
        const f32x4 zf = *(const f32x4*)(Z + (hcol + Hh) * ZP + m0);
        const f32x4 zg = *(const f32x4*)(Z + (hcol + 2 * Hh) * ZP + m0);
        const f32x4 zo = *(const f32x4*)(Z + (hcol + 3 * Hh) * ZP + m0);
        const f32x4 mk = *(const f32x4*)(maskbuf + m0);
#pragma unroll
        for (int r = 0; r < 4; r++) {
            float cn = sigmoid_f(zf[r]) * creg[r] + sigmoid_f(zi[r]) * tanh_f(zg[r]);
            float hn = sigmoid_f(zo[r]) * tanh_f(cn);
            bool mm = (mk[r] != 0.0f);
            creg[r] = mm ? cn : creg[r];
            hreg[r] = mm ? hn : hreg[r];
            h16[(m0 + r) * HP + hcol] = (_Float16)hreg[r];
            hs[((size_t)(b0 + m0 + r) * Ss + tcur) * (2 * Hh) + dir * Hh + hcol] = hreg[r];
        }
        if (i == Ss - 1 && dir == 0) {
#pragma unroll
            for (int r = 0; r < 4; r++)
                hfwd[(size_t)(b0 + m0 + r) * Hh + hcol] = hreg[r];
        }
        __syncthreads();
    }
}

// ---------------- Kernel 3: qtot = h_fwd @ Wq + bq + bk ----------------
__global__ void q_kernel(const float* __restrict__ hfwd, const float* __restrict__ Wq,
                         const float* __restrict__ bq, const float* __restrict__ bk,
                         float* __restrict__ qtot) {
    __shared__ float hl[Hh];
    int b = blockIdx.x, j = threadIdx.x;
    hl[j] = hfwd[(size_t)b * Hh + j];
    __syncthreads();
    float q = bq[j] + bk[j];
#pragma unroll
    for (int k = 0; k < Hh; k++) q += hl[k] * Wq[k * Hh + j];
    qtot[(size_t)b * Hh + j] = q;
}

// ---------------- Kernel 4: energy = tanh(out@Wk + qtot) @ We ----------------
__global__ void __launch_bounds__(256, 2)
energy_kernel(const float* __restrict__ hs, const float* __restrict__ qtot,
              const float* __restrict__ Wk, const float* __restrict__ We,
              float* __restrict__ energy)
{
    __shared__ __align__(16) float olds[EROWS][2 * Hh];
    __shared__ __align__(16) float keybuf[EROWS][Hh];
    __shared__ float red[EROWS][8];
    int b = blockIdx.x / (Ss / EROWS);
    int s0 = (blockIdx.x % (Ss / EROWS)) * EROWS;
    int tid = threadIdx.x;

    const float4* src4 = (const float4*)(hs + ((size_t)b * Ss + s0) * (2 * Hh));
    float4* dst4 = (float4*)&olds[0][0];
    for (int i = tid; i < EROWS * 2 * Hh / 4; i += 256) dst4[i] = src4[i];
    __syncthreads();

    int j = tid & 127;
    int half = tid >> 7;
    float wk[Hh];
#pragma unroll
    for (int k = 0; k < Hh; k++) wk[k] = Wk[(half * Hh + k) * Hh + j];
    float qj = qtot[(size_t)b * Hh + j];
    float acc[EROWS];
#pragma unroll
    for (int r = 0; r < EROWS; r++) acc[r] = (half == 0) ? qj : 0.0f;

#pragma unroll
    for (int r = 0; r < EROWS; r++) {
        const float4* o4 = (const float4*)&olds[r][half * Hh];
#pragma unroll
        for (int k = 0; k < Hh / 4; k++) {
            float4 o = o4[k];
            acc[r] += o.x * wk[4 * k] + o.y * wk[4 * k + 1] + o.z * wk[4 * k + 2] + o.w * wk[4 * k + 3];
        }
    }
    if (half == 1) {
#pragma unroll
        for (int r = 0; r < EROWS; r++) keybuf[r][j] = acc[r];
    }
    __syncthreads();
    if (half == 0) {
        float wej = We[j];
#pragma unroll
        for (int r = 0; r < EROWS; r++) {
            float key = acc[r] + keybuf[r][j];
            keybuf[r][j] = tanh_f(key) * wej;
        }
    }
    __syncthreads();
    if (tid < EROWS * 8) {
        int r = tid >> 3, l = tid & 7;
        float s = 0.0f;
#pragma unroll
        for (int i2 = 0; i2 < 16; i2++) s += keybuf[r][l * 16 + i2];
        red[r][l] = s;
    }
    __syncthreads();
    if (tid < EROWS) {
        float e = 0.0f;
#pragma unroll
        for (int l = 0; l < 8; l++) e += red[tid][l];
        energy[(size_t)b * Ss + s0 + tid] = e;
    }
}

// ---------------- Kernel 5: masked softmax over S + weighted context ----------------
__global__ void __launch_bounds__(256)
ctx_kernel(const float* __restrict__ energy, const float* __restrict__ maskf,
           const float* __restrict__ hs, float* __restrict__ outp)
{
    __shared__ __align__(16) float w[Ss];
    __shared__ float redm[4], reds[4];
    int b = blockIdx.x, tid = threadIdx.x;

    float e0 = energy[(size_t)b * Ss + tid];
    float e1 = energy[(size_t)b * Ss + tid + 256];
    float m0 = maskf[(size_t)b * Ss + tid];
    float m1 = maskf[(size_t)b * Ss + tid + 256];
    e0 += (1.0f - m0) * -1e9f;
    e1 += (1.0f - m1) * -1e9f;

    float mx = fmaxf(e0, e1);
#pragma unroll
    for (int off = 32; off > 0; off >>= 1) mx = fmaxf(mx, __shfl_down(mx, off));
    if ((tid & 63) == 0) redm[tid >> 6] = mx;
    __syncthreads();
    mx = fmaxf(fmaxf(redm[0], redm[1]), fmaxf(redm[2], redm[3]));

    float p0 = __expf(e0 - mx), p1 = __expf(e1 - mx);
    float sm = p0 + p1;
#pragma unroll
    for (int off = 32; off > 0; off >>= 1) sm += __shfl_down(sm, off);
    if ((tid & 63) == 0) reds[tid >> 6] = sm;
    __syncthreads();
    sm = reds[0] + reds[1] + reds[2] + reds[3];
    float inv = 1.0f / sm;
    w[tid] = p0 * inv;
    w[tid + 256] = p1 * inv;
    __syncthreads();

    float ctx = 0.0f;
    const float* hsb = hs + (size_t)b * Ss * (2 * Hh) + tid;
    const float4* w4 = (const float4*)w;
#pragma unroll 2
    for (int s4i = 0; s4i < Ss / 4; s4i++) {
        float4 ww = w4[s4i];
        size_t base = (size_t)(s4i * 4) * (2 * Hh);
        ctx += ww.x * hsb[base];
        ctx += ww.y * hsb[base + 256];
        ctx += ww.z * hsb[base + 512];
        ctx += ww.w * hsb[base + 768];
    }
    outp[(size_t)b * (2 * Hh) + tid] = ctx;
}

// ---------------- Launcher ----------------
extern "C" void kernel_launch(void* const* d_in, const int* in_sizes, int n_in,
                              void* d_out, int out_size, void* d_ws, size_t ws_size,
                              hipStream_t stream) {
    const int*   tags  = (const int*)d_in[0];
    const float* skips = (const float*)d_in[1];
    const float* table = (const float*)d_in[2];
    const float* Kf    = (const float*)d_in[3];
    const float* Rf    = (const float*)d_in[4];
    const float* Skf   = (const float*)d_in[5];
    const float* bf    = (const float*)d_in[6];
    const float* Kb    = (const float*)d_in[7];
    const float* Rb    = (const float*)d_in[8];
    const float* Skb   = (const float*)d_in[9];
    const float* bb    = (const float*)d_in[10];
    const float* Wk    = (const float*)d_in[11];
    const float* bk    = (const float*)d_in[12];
    const float* Wq    = (const float*)d_in[13];
    const float* bq    = (const float*)d_in[14];
    const float* We    = (const float*)d_in[15];

    char* ws = (char*)d_ws;
    _Float16* gru16 = (_Float16*)ws; ws += (size_t)BSn * 32 * 2;    // 8.4 MB, [t][b][32]
    float* maskf  = (float*)ws;  ws += (size_t)BSn * 4;             // 0.5 MB
    float* hs     = (float*)ws;  ws += (size_t)BSn * 2 * Hh * 4;    // 134.2 MB
    float* hfwd   = (float*)ws;  ws += (size_t)Bb * Hh * 4;
    float* qtot   = (float*)ws;  ws += (size_t)Bb * Hh * 4;
    float* energy = (float*)ws;  ws += (size_t)BSn * 4;

    pool_kernel<<<BSn / 8, 256, 0, stream>>>(tags, table, gru16, maskf);
    scan_kernel<<<32, 512, 0, stream>>>(gru16, skips, maskf,
                                        Kf, Rf, Skf, bf,
                                        Kb, Rb, Skb, bb,
                                        hs, hfwd);
    q_kernel<<<Bb, Hh, 0, stream>>>(hfwd, Wq, bq, bk, qtot);
    energy_kernel<<<Bb * (Ss / EROWS), 256, 0, stream>>>(hs, qtot, Wk, We, energy);
    ctx_kernel<<<Bb, 256, 0, stream>>>(energy, maskf, hs, (float*)d_out);
}

// Round 4
// 1350.255 us; speedup vs baseline: 1.8698x; 1.1861x over previous
//
#include <hip/hip_runtime.h>
#include <math.h>

#define Bb 256
#define Ss 512
#define Tt 20
#define Ee 25
#define Hh 128
#define SKIPn 64
#define H4n 512
#define BSn (Bb*Ss)
#define EROWS 16
#define MG 16            // batch rows per scan block
#define HP 136           // h16 LDS row pitch in halves (128 + 8 pad)

typedef _Float16 f16x8 __attribute__((ext_vector_type(8)));
typedef float f32x4 __attribute__((ext_vector_type(4)));

__device__ __forceinline__ float sigmoid_f(float x) {
    return 1.0f / (1.0f + __expf(-x));
}
__device__ __forceinline__ float tanh_f(float x) {
    float a = fabsf(x);
    float e = __expf(-2.0f * a);
    float r = (1.0f - e) / (1.0f + e);
    return copysignf(r, x);
}
// Barrier that waits only on LDS ops (lgkmcnt(0)); leaves vmcnt in flight.
// 0xC07F = vmcnt 63 | expcnt 7 | lgkmcnt 0 (gfx9 encoding).
__device__ __forceinline__ void lgkm_barrier() {
    __asm__ __volatile__("" ::: "memory");
    __builtin_amdgcn_s_waitcnt(0xC07F);
    __builtin_amdgcn_s_barrier();
    __asm__ __volatile__("" ::: "memory");
}

// ---------------- Kernel 1: embedding mean-pool (fp16 out, [t][b][32]) + masks ----------------
__global__ void pool_kernel(const int* __restrict__ tags,
                            const float* __restrict__ table,
                            _Float16* __restrict__ gru16, float* __restrict__ maskf,
                            float* __restrict__ maskt) {
    int group = blockIdx.x * 8 + (threadIdx.x >> 5);
    int lane = threadIdx.x & 31;
    if (group >= BSn) return;
    int b = group >> 9;          // group = b*Ss + t
    int t = group & (Ss - 1);
    const int* tg = tags + (size_t)group * Tt;
    float acc = 0.0f;
    int cnt = 0;
    int first = tg[0];
#pragma unroll
    for (int tt = 0; tt < Tt; tt++) {
        int tag = tg[tt];
        if (tag != 0) {
            cnt++;
            if (lane < Ee) acc += table[(size_t)tag * Ee + lane];
        }
    }
    float scale = 1.0f / (float)(cnt > 0 ? cnt : 1);
    float v = (lane < Ee) ? acc * scale : 0.0f;
    gru16[((size_t)t * Bb + b) * 32 + lane] = (_Float16)v;
    if (lane == 0) {
        float m = (first != 0) ? 1.0f : 0.0f;
        maskf[group] = m;                       // [b][t] for ctx
        maskt[(size_t)t * Bb + b] = m;          // [t][b] for scan
    }
}

// ---------------- Kernel 2: bidirectional LSTM scan via MFMA fp16 ----------------
// Grid = 32 blocks (dir, 16-batch-group), 512 threads = 8 waves.
// Gate-interleaved mapping: wave w owns h-columns 16w..16w+15; its 4 n-tiles
// are the 4 gates of those columns -> gates computed directly from MFMA
// C-registers (no Z LDS, no transpose). h feedback via double-buffered fp16
// LDS; barriers wait lgkmcnt only (global stores/prefetch stay in flight).
__global__ void __launch_bounds__(512)
__attribute__((amdgpu_waves_per_eu(2, 2)))
scan_kernel(const _Float16* __restrict__ gru16, const float* __restrict__ skips,
            const float* __restrict__ maskt,
            const float* __restrict__ Kf, const float* __restrict__ Rf,
            const float* __restrict__ Skf, const float* __restrict__ bf,
            const float* __restrict__ Kb, const float* __restrict__ Rb,
            const float* __restrict__ Skb, const float* __restrict__ bb,
            float* __restrict__ hs, float* __restrict__ hfwd)
{
    __shared__ __align__(16) _Float16 h16[2 * MG * HP];

    const int tid = threadIdx.x;
    const int lane = tid & 63;
    const int w = tid >> 6;          // wave 0..7: h-columns 16w..16w+15
    const int l16 = lane & 15;
    const int q = lane >> 4;         // 0..3
    const int bg = blockIdx.x & 15;
    const int dir = blockIdx.x >> 4;
    const int b0 = bg * MG;
    const int hcol = 16 * w + l16;   // this thread's h column

    const float* Kw = dir ? Kb : Kf;
    const float* Rw = dir ? Rb : Rf;
    const float* Sw = dir ? Skb : Skf;
    const float* bw = dir ? bb : bf;

    // ---- B-fragments, gate-interleaved: bfr[kt][g][j] = W[32kt+8q+j][g*128+hcol]
    f16x8 bfr[7][4];
#pragma unroll
    for (int kt = 0; kt < 7; kt++) {
#pragma unroll
        for (int g = 0; g < 4; g++) {
            const int n = g * Hh + hcol;
            f16x8 v;
#pragma unroll
            for (int j = 0; j < 8; j++) {
                const int k = 32 * kt + 8 * q + j;
                float x;
                if (k < 32)        x = (k < Ee) ? Kw[k * H4n + n] : 0.0f;
                else if (k < 160)  x = Rw[(k - 32) * H4n + n];
                else               x = Sw[(k - 160) * H4n + n];
                v[j] = (_Float16)x;
            }
            bfr[kt][g] = v;
        }
    }
    float biasv[4];
#pragma unroll
    for (int g = 0; g < 4; g++) biasv[g] = bw[g * Hh + hcol];

    // zero both h buffers
    for (int idx = tid; idx < 2 * MG * HP; idx += 512) h16[idx] = (_Float16)0.0f;

    const float* srow = skips + (size_t)(b0 + l16) * Ss * SKIPn;
    float creg[4] = {0.f, 0.f, 0.f, 0.f};
    float hreg[4] = {0.f, 0.f, 0.f, 0.f};

    // 2-slot, depth-2 prefetch state
    f16x8 xA, xB;
    f32x4 sA0, sA1, sA2, sA3, sB0, sB1, sB2, sB3;
    f32x4 mA, mB;

    auto issue = [&](f16x8& xf, f32x4& s0, f32x4& s1, f32x4& s2, f32x4& s3,
                     f32x4& mk, int i) {
        const int ii = (i < Ss) ? i : (Ss - 1);
        const int t = dir ? (Ss - 1 - ii) : ii;
        xf = *(const f16x8*)(gru16 + ((size_t)t * Bb + b0 + l16) * 32 + 8 * q);
        const float* sp = srow + (size_t)t * SKIPn;
        s0 = *(const f32x4*)(sp + 8 * q);
        s1 = *(const f32x4*)(sp + 8 * q + 4);
        s2 = *(const f32x4*)(sp + 32 + 8 * q);
        s3 = *(const f32x4*)(sp + 32 + 8 * q + 4);
        mk = *(const f32x4*)(maskt + (size_t)t * Bb + b0 + 4 * q);
    };

    issue(xA, sA0, sA1, sA2, sA3, mA, 0);
    issue(xB, sB0, sB1, sB2, sB3, mB, 1);
    __syncthreads();

    auto body = [&](int i, f16x8& xf, f32x4& s0, f32x4& s1, f32x4& s2, f32x4& s3,
                    f32x4& mkv) {
        const int tcur = dir ? (Ss - 1 - i) : i;
        // build current fragments from slot
        const f16x8 ax = xf;
        f16x8 as0, as1;
#pragma unroll
        for (int j = 0; j < 4; j++) {
            as0[j]     = (_Float16)s0[j];
            as0[j + 4] = (_Float16)s1[j];
            as1[j]     = (_Float16)s2[j];
            as1[j + 4] = (_Float16)s3[j];
        }
        const f32x4 mk = mkv;
        // refill slot for step i+2 (consumed two iterations from now)
        issue(xf, s0, s1, s2, s3, mkv, i + 2);

        // ---- MFMA: acc[g] = bias + x/s terms, then h terms
        f32x4 acc[4];
#pragma unroll
        for (int g = 0; g < 4; g++) {
            f32x4 a = {biasv[g], biasv[g], biasv[g], biasv[g]};
            acc[g] = a;
        }
#pragma unroll
        for (int g = 0; g < 4; g++)
            acc[g] = __builtin_amdgcn_mfma_f32_16x16x32_f16(ax, bfr[0][g], acc[g], 0, 0, 0);
#pragma unroll
        for (int g = 0; g < 4; g++)
            acc[g] = __builtin_amdgcn_mfma_f32_16x16x32_f16(as0, bfr[5][g], acc[g], 0, 0, 0);
#pragma unroll
        for (int g = 0; g < 4; g++)
            acc[g] = __builtin_amdgcn_mfma_f32_16x16x32_f16(as1, bfr[6][g], acc[g], 0, 0, 0);

        const _Float16* hb = h16 + (i & 1) * (MG * HP);
#pragma unroll
        for (int kt = 0; kt < 4; kt++) {
            const f16x8 ah = *(const f16x8*)(hb + l16 * HP + 32 * kt + 8 * q);
#pragma unroll
            for (int g = 0; g < 4; g++)
                acc[g] = __builtin_amdgcn_mfma_f32_16x16x32_f16(ah, bfr[1 + kt][g], acc[g], 0, 0, 0);
        }

        // ---- gates in-register: thread owns rows 4q..4q+3 of column hcol
        _Float16* hw = h16 + ((i + 1) & 1) * (MG * HP);
#pragma unroll
        for (int r = 0; r < 4; r++) {
            const float zi = acc[0][r], zf = acc[1][r];
            const float zg = acc[2][r], zo = acc[3][r];
            float cn = sigmoid_f(zf) * creg[r] + sigmoid_f(zi) * tanh_f(zg);
            float hn = sigmoid_f(zo) * tanh_f(cn);
            const bool mm = (mk[r] != 0.0f);
            creg[r] = mm ? cn : creg[r];
            hreg[r] = mm ? hn : hreg[r];
            hw[(4 * q + r) * HP + hcol] = (_Float16)hreg[r];
            hs[((size_t)(b0 + 4 * q + r) * Ss + tcur) * (2 * Hh) + dir * Hh + hcol] = hreg[r];
        }
        lgkm_barrier();
    };

#pragma unroll 1
    for (int i = 0; i < Ss; i += 2) {
        body(i,     xA, sA0, sA1, sA2, sA3, mA);
        body(i + 1, xB, sB0, sB1, sB2, sB3, mB);
    }

    if (dir == 0) {
#pragma unroll
        for (int r = 0; r < 4; r++)
            hfwd[(size_t)(b0 + 4 * q + r) * Hh + hcol] = hreg[r];
    }
}

// ---------------- Kernel 3: qtot = h_fwd @ Wq + bq + bk ----------------
__global__ void q_kernel(const float* __restrict__ hfwd, const float* __restrict__ Wq,
                         const float* __restrict__ bq, const float* __restrict__ bk,
                         float* __restrict__ qtot) {
    __shared__ float hl[Hh];
    int b = blockIdx.x, j = threadIdx.x;
    hl[j] = hfwd[(size_t)b * Hh + j];
    __syncthreads();
    float q = bq[j] + bk[j];
#pragma unroll
    for (int k = 0; k < Hh; k++) q += hl[k] * Wq[k * Hh + j];
    qtot[(size_t)b * Hh + j] = q;
}

// ---------------- Kernel 4: energy = tanh(out@Wk + qtot) @ We ----------------
__global__ void __launch_bounds__(256, 2)
energy_kernel(const float* __restrict__ hs, const float* __restrict__ qtot,
              const float* __restrict__ Wk, const float* __restrict__ We,
              float* __restrict__ energy)
{
    __shared__ __align__(16) float olds[EROWS][2 * Hh];
    __shared__ __align__(16) float keybuf[EROWS][Hh];
    __shared__ float red[EROWS][8];
    int b = blockIdx.x / (Ss / EROWS);
    int s0 = (blockIdx.x % (Ss / EROWS)) * EROWS;
    int tid = threadIdx.x;

    const float4* src4 = (const float4*)(hs + ((size_t)b * Ss + s0) * (2 * Hh));
    float4* dst4 = (float4*)&olds[0][0];
    for (int i = tid; i < EROWS * 2 * Hh / 4; i += 256) dst4[i] = src4[i];
    __syncthreads();

    int j = tid & 127;
    int half = tid >> 7;
    float wk[Hh];
#pragma unroll
    for (int k = 0; k < Hh; k++) wk[k] = Wk[(half * Hh + k) * Hh + j];
    float qj = qtot[(size_t)b * Hh + j];
    float acc[EROWS];
#pragma unroll
    for (int r = 0; r < EROWS; r++) acc[r] = (half == 0) ? qj : 0.0f;

#pragma unroll
    for (int r = 0; r < EROWS; r++) {
        const float4* o4 = (const float4*)&olds[r][half * Hh];
#pragma unroll
        for (int k = 0; k < Hh / 4; k++) {
            float4 o = o4[k];
            acc[r] += o.x * wk[4 * k] + o.y * wk[4 * k + 1] + o.z * wk[4 * k + 2] + o.w * wk[4 * k + 3];
        }
    }
    if (half == 1) {
#pragma unroll
        for (int r = 0; r < EROWS; r++) keybuf[r][j] = acc[r];
    }
    __syncthreads();
    if (half == 0) {
        float wej = We[j];
#pragma unroll
        for (int r = 0; r < EROWS; r++) {
            float key = acc[r] + keybuf[r][j];
            keybuf[r][j] = tanh_f(key) * wej;
        }
    }
    __syncthreads();
    if (tid < EROWS * 8) {
        int r = tid >> 3, l = tid & 7;
        float s = 0.0f;
#pragma unroll
        for (int i2 = 0; i2 < 16; i2++) s += keybuf[r][l * 16 + i2];
        red[r][l] = s;
    }
    __syncthreads();
    if (tid < EROWS) {
        float e = 0.0f;
#pragma unroll
        for (int l = 0; l < 8; l++) e += red[tid][l];
        energy[(size_t)b * Ss + s0 + tid] = e;
    }
}

// ---------------- Kernel 5: masked softmax over S + weighted context ----------------
__global__ void __launch_bounds__(256)
ctx_kernel(const float* __restrict__ energy, const float* __restrict__ maskf,
           const float* __restrict__ hs, float* __restrict__ outp)
{
    __shared__ __align__(16) float w[Ss];
    __shared__ float redm[4], reds[4];
    int b = blockIdx.x, tid = threadIdx.x;

    float e0 = energy[(size_t)b * Ss + tid];
    float e1 = energy[(size_t)b * Ss + tid + 256];
    float m0 = maskf[(size_t)b * Ss + tid];
    float m1 = maskf[(size_t)b * Ss + tid + 256];
    e0 += (1.0f - m0) * -1e9f;
    e1 += (1.0f - m1) * -1e9f;

    float mx = fmaxf(e0, e1);
#pragma unroll
    for (int off = 32; off > 0; off >>= 1) mx = fmaxf(mx, __shfl_down(mx, off));
    if ((tid & 63) == 0) redm[tid >> 6] = mx;
    __syncthreads();
    mx = fmaxf(fmaxf(redm[0], redm[1]), fmaxf(redm[2], redm[3]));

    float p0 = __expf(e0 - mx), p1 = __expf(e1 - mx);
    float sm = p0 + p1;
#pragma unroll
    for (int off = 32; off > 0; off >>= 1) sm += __shfl_down(sm, off);
    if ((tid & 63) == 0) reds[tid >> 6] = sm;
    __syncthreads();
    sm = reds[0] + reds[1] + reds[2] + reds[3];
    float inv = 1.0f / sm;
    w[tid] = p0 * inv;
    w[tid + 256] = p1 * inv;
    __syncthreads();

    float ctx = 0.0f;
    const float* hsb = hs + (size_t)b * Ss * (2 * Hh) + tid;
    const float4* w4 = (const float4*)w;
#pragma unroll 2
    for (int s4i = 0; s4i < Ss / 4; s4i++) {
        float4 ww = w4[s4i];
        size_t base = (size_t)(s4i * 4) * (2 * Hh);
        ctx += ww.x * hsb[base];
        ctx += ww.y * hsb[base + 256];
        ctx += ww.z * hsb[base + 512];
        ctx += ww.w * hsb[base + 768];
    }
    outp[(size_t)b * (2 * Hh) + tid] = ctx;
}

// ---------------- Launcher ----------------
extern "C" void kernel_launch(void* const* d_in, const int* in_sizes, int n_in,
                              void* d_out, int out_size, void* d_ws, size_t ws_size,
                              hipStream_t stream) {
    const int*   tags  = (const int*)d_in[0];
    const float* skips = (const float*)d_in[1];
    const float* table = (const float*)d_in[2];
    const float* Kf    = (const float*)d_in[3];
    const float* Rf    = (const float*)d_in[4];
    const float* Skf   = (const float*)d_in[5];
    const float* bf    = (const float*)d_in[6];
    const float* Kb    = (const float*)d_in[7];
    const float* Rb    = (const float*)d_in[8];
    const float* Skb   = (const float*)d_in[9];
    const float* bb    = (const float*)d_in[10];
    const float* Wk    = (const float*)d_in[11];
    const float* bk    = (const float*)d_in[12];
    const float* Wq    = (const float*)d_in[13];
    const float* bq    = (const float*)d_in[14];
    const float* We    = (const float*)d_in[15];

    char* ws = (char*)d_ws;
    _Float16* gru16 = (_Float16*)ws; ws += (size_t)BSn * 32 * 2;    // 8.4 MB, [t][b][32]
    float* maskf  = (float*)ws;  ws += (size_t)BSn * 4;             // 0.5 MB, [b][t]
    float* maskt  = (float*)ws;  ws += (size_t)BSn * 4;             // 0.5 MB, [t][b]
    float* hs     = (float*)ws;  ws += (size_t)BSn * 2 * Hh * 4;    // 134.2 MB
    float* hfwd   = (float*)ws;  ws += (size_t)Bb * Hh * 4;
    float* qtot   = (float*)ws;  ws += (size_t)Bb * Hh * 4;
    float* energy = (float*)ws;  ws += (size_t)BSn * 4;

    pool_kernel<<<BSn / 8, 256, 0, stream>>>(tags, table, gru16, maskf, maskt);
    scan_kernel<<<32, 512, 0, stream>>>(gru16, skips, maskt,
                                        Kf, Rf, Skf, bf,
                                        Kb, Rb, Skb, bb,
                                        hs, hfwd);
    q_kernel<<<Bb, Hh, 0, stream>>>(hfwd, Wq, bq, bk, qtot);
    energy_kernel<<<Bb * (Ss / EROWS), 256, 0, stream>>>(hs, qtot, Wk, We, energy);
    ctx_kernel<<<Bb, 256, 0, stream>>>(energy, maskf, hs, (float*)d_out);
}

// Round 6
// 885.747 us; speedup vs baseline: 2.8504x; 1.5244x over previous
//
#include <hip/hip_runtime.h>
#include <math.h>

#define Bb 256
#define Ss 512
#define Tt 20
#define Ee 25
#define Hh 128
#define SKIPn 64
#define H4n 512
#define BSn (Bb*Ss)
#define MG 16            // batch rows per scan block
#define HP 136           // h16 LDS row pitch in halves (128 + 8 pad)

typedef _Float16 f16x8 __attribute__((ext_vector_type(8)));
typedef float f32x4 __attribute__((ext_vector_type(4)));

__device__ __forceinline__ float rcpf(float x) { return __builtin_amdgcn_rcpf(x); }

// Barrier that waits only on LDS ops (lgkmcnt(0)); leaves vmcnt in flight.
__device__ __forceinline__ void lgkm_barrier() {
    __asm__ __volatile__("" ::: "memory");
    __builtin_amdgcn_s_waitcnt(0xC07F);
    __builtin_amdgcn_s_barrier();
    __asm__ __volatile__("" ::: "memory");
}

// ---------------- Kernel 1: embedding mean-pool (fp16 out, [t][b][32]) + masks ----------------
__global__ void pool_kernel(const int* __restrict__ tags,
                            const float* __restrict__ table,
                            _Float16* __restrict__ gru16, float* __restrict__ maskf,
                            float* __restrict__ maskt) {
    int group = blockIdx.x * 8 + (threadIdx.x >> 5);
    int lane = threadIdx.x & 31;
    if (group >= BSn) return;
    int b = group >> 9;          // group = b*Ss + t
    int t = group & (Ss - 1);
    const int* tg = tags + (size_t)group * Tt;
    float acc = 0.0f;
    int cnt = 0;
    int first = tg[0];
#pragma unroll
    for (int tt = 0; tt < Tt; tt++) {
        int tag = tg[tt];
        if (tag != 0) {
            cnt++;
            if (lane < Ee) acc += table[(size_t)tag * Ee + lane];
        }
    }
    float scale = rcpf((float)(cnt > 0 ? cnt : 1));
    float v = (lane < Ee) ? acc * scale : 0.0f;
    gru16[((size_t)t * Bb + b) * 32 + lane] = (_Float16)v;
    if (lane == 0) {
        float m = (first != 0) ? 1.0f : 0.0f;
        maskf[group] = m;                       // [b][t] for ctx
        maskt[(size_t)t * Bb + b] = m;          // [t][b] for scan
    }
}

// ---------------- Kernel 1b: skips fp32 -> fp16 flat copy ----------------
__global__ void __launch_bounds__(256)
cvt_kernel(const float* __restrict__ in, _Float16* __restrict__ out) {
    size_t i = ((size_t)blockIdx.x * 256 + threadIdx.x) * 8;
    f32x4 a = *(const f32x4*)(in + i);
    f32x4 b = *(const f32x4*)(in + i + 4);
    f16x8 o;
#pragma unroll
    for (int j = 0; j < 4; j++) { o[j] = (_Float16)a[j]; o[j + 4] = (_Float16)b[j]; }
    *(f16x8*)(out + i) = o;
}

// ---------------- Kernel 2: bidirectional LSTM scan via MFMA fp16 ----------------
// Grid = 32 blocks (dir, 16-batch-group), 512 threads = 8 waves.
// Gate-interleaved: wave w owns h-cols 16w..16w+15, its 4 n-tiles = 4 gates
// -> gates straight from MFMA C-regs. Division-free gate math (exp+rcp).
__global__ void __launch_bounds__(512)
__attribute__((amdgpu_waves_per_eu(2, 2)))
scan_kernel(const _Float16* __restrict__ gru16, const _Float16* __restrict__ skips16,
            const float* __restrict__ maskt,
            const float* __restrict__ Kf, const float* __restrict__ Rf,
            const float* __restrict__ Skf, const float* __restrict__ bf,
            const float* __restrict__ Kb, const float* __restrict__ Rb,
            const float* __restrict__ Skb, const float* __restrict__ bb,
            _Float16* __restrict__ hs16, float* __restrict__ hfwd)
{
    __shared__ __align__(16) _Float16 h16[2 * MG * HP];

    const int tid = threadIdx.x;
    const int lane = tid & 63;
    const int w = tid >> 6;
    const int l16 = lane & 15;
    const int q = lane >> 4;
    const int bg = blockIdx.x & 15;
    const int dir = blockIdx.x >> 4;
    const int b0 = bg * MG;
    const int hcol = 16 * w + l16;

    const float* Kw = dir ? Kb : Kf;
    const float* Rw = dir ? Rb : Rf;
    const float* Sw = dir ? Skb : Skf;
    const float* bw = dir ? bb : bf;

    // B-fragments, gate-interleaved: bfr[kt][g][j] = W[32kt+8q+j][g*128+hcol]
    f16x8 bfr[7][4];
#pragma unroll
    for (int kt = 0; kt < 7; kt++) {
#pragma unroll
        for (int g = 0; g < 4; g++) {
            const int n = g * Hh + hcol;
            f16x8 v;
#pragma unroll
            for (int j = 0; j < 8; j++) {
                const int k = 32 * kt + 8 * q + j;
                float x;
                if (k < 32)        x = (k < Ee) ? Kw[k * H4n + n] : 0.0f;
                else if (k < 160)  x = Rw[(k - 32) * H4n + n];
                else               x = Sw[(k - 160) * H4n + n];
                v[j] = (_Float16)x;
            }
            bfr[kt][g] = v;
        }
    }
    float biasv[4];
#pragma unroll
    for (int g = 0; g < 4; g++) biasv[g] = bw[g * Hh + hcol];

    for (int idx = tid; idx < 2 * MG * HP; idx += 512) h16[idx] = (_Float16)0.0f;

    const _Float16* srow = skips16 + (size_t)(b0 + l16) * Ss * SKIPn;
    float creg[4] = {0.f, 0.f, 0.f, 0.f};
    float hreg[4] = {0.f, 0.f, 0.f, 0.f};

    // hs16 offset in halves; per-step delta +-256 (rows via +r*Ss*256)
    unsigned off = ((unsigned)(b0 + 4 * q) * Ss + (dir ? Ss - 1 : 0)) * (2 * Hh) + dir * Hh + hcol;
    const int odelta = dir ? -(2 * Hh) : (2 * Hh);

    // 2-slot depth-2 prefetch
    f16x8 xA, xB, sA0, sA1, sB0, sB1;
    f32x4 mA, mB;
    auto issue = [&](f16x8& xf, f16x8& s0, f16x8& s1, f32x4& mk, int i) {
        const int ii = (i < Ss) ? i : (Ss - 1);
        const int t = dir ? (Ss - 1 - ii) : ii;
        xf = *(const f16x8*)(gru16 + ((size_t)t * Bb + b0 + l16) * 32 + 8 * q);
        const _Float16* sp = srow + (size_t)t * SKIPn;
        s0 = *(const f16x8*)(sp + 8 * q);
        s1 = *(const f16x8*)(sp + 32 + 8 * q);
        mk = *(const f32x4*)(maskt + (size_t)t * Bb + b0 + 4 * q);
    };
    issue(xA, sA0, sA1, mA, 0);
    issue(xB, sB0, sB1, mB, 1);
    __syncthreads();

    auto body = [&](int i, f16x8& xf, f16x8& s0, f16x8& s1, f32x4& mkv) {
        const f16x8 ax = xf, as0 = s0, as1 = s1;
        const f32x4 mk = mkv;
        issue(xf, s0, s1, mkv, i + 2);   // refill for step i+2

        f32x4 acc[4];
#pragma unroll
        for (int g = 0; g < 4; g++) {
            f32x4 a = {biasv[g], biasv[g], biasv[g], biasv[g]};
            acc[g] = a;
        }
#pragma unroll
        for (int g = 0; g < 4; g++) {
            acc[g] = __builtin_amdgcn_mfma_f32_16x16x32_f16(ax,  bfr[0][g], acc[g], 0, 0, 0);
            acc[g] = __builtin_amdgcn_mfma_f32_16x16x32_f16(as0, bfr[5][g], acc[g], 0, 0, 0);
            acc[g] = __builtin_amdgcn_mfma_f32_16x16x32_f16(as1, bfr[6][g], acc[g], 0, 0, 0);
        }
        const _Float16* hb = h16 + (i & 1) * (MG * HP);
#pragma unroll
        for (int kt = 0; kt < 4; kt++) {
            const f16x8 ah = *(const f16x8*)(hb + l16 * HP + 32 * kt + 8 * q);
#pragma unroll
            for (int g = 0; g < 4; g++)
                acc[g] = __builtin_amdgcn_mfma_f32_16x16x32_f16(ah, bfr[1 + kt][g], acc[g], 0, 0, 0);
        }

        _Float16* hw = h16 + ((i + 1) & 1) * (MG * HP);
#pragma unroll
        for (int r = 0; r < 4; r++) {
            const float zi = acc[0][r], zf = acc[1][r];
            const float zg = fmaxf(acc[2][r], -40.0f), zo = acc[3][r];
            const float ei = __expf(-zi);
            const float eg = __expf(-2.0f * zg);
            const float ig = (1.0f - eg) * rcpf((1.0f + ei) * (1.0f + eg));
            const float f  = rcpf(1.0f + __expf(-zf));
            const float cn = fmaf(f, creg[r], ig);
            const float cc = fminf(fmaxf(cn, -15.0f), 15.0f);
            const float eo = __expf(-zo);
            const float ec = __expf(-2.0f * cc);
            const float hn = (1.0f - ec) * rcpf((1.0f + eo) * (1.0f + ec));
            const bool mm = (mk[r] != 0.0f);
            creg[r] = mm ? cn : creg[r];
            hreg[r] = mm ? hn : hreg[r];
            hw[(4 * q + r) * HP + hcol] = (_Float16)hreg[r];
            hs16[off + (unsigned)r * (Ss * 2 * Hh)] = (_Float16)hreg[r];
        }
        off += odelta;
        lgkm_barrier();
    };

#pragma unroll 1
    for (int i = 0; i < Ss; i += 2) {
        body(i,     xA, sA0, sA1, mA);
        body(i + 1, xB, sB0, sB1, mB);
    }

    if (dir == 0) {
#pragma unroll
        for (int r = 0; r < 4; r++)
            hfwd[(size_t)(b0 + 4 * q + r) * Hh + hcol] = hreg[r];
    }
}

// ---------------- Kernel 3: qtot = h_fwd @ Wq + bq + bk ----------------
__global__ void q_kernel(const float* __restrict__ hfwd, const float* __restrict__ Wq,
                         const float* __restrict__ bq, const float* __restrict__ bk,
                         float* __restrict__ qtot) {
    __shared__ float hl[Hh];
    int b = blockIdx.x, j = threadIdx.x;
    hl[j] = hfwd[(size_t)b * Hh + j];
    __syncthreads();
    float q = bq[j] + bk[j];
#pragma unroll
    for (int k = 0; k < Hh; k++) q += hl[k] * Wq[k * Hh + j];
    qtot[(size_t)b * Hh + j] = q;
}

// ---------------- Kernel 4: energy via MFMA: tanh(out@Wk + qtot) @ We ----------------
// Grid = Bb * 32 blocks (16 s-rows each), 512 threads; wave w owns j-tile w.
__global__ void __launch_bounds__(512)
energy_kernel(const _Float16* __restrict__ hs16, const float* __restrict__ qtot,
              const float* __restrict__ Wk, const float* __restrict__ We,
              float* __restrict__ energy)
{
    __shared__ float redl[8 * 16];
    const int tid = threadIdx.x;
    const int lane = tid & 63;
    const int w = tid >> 6;
    const int l16 = lane & 15;
    const int q = lane >> 4;
    const int b = blockIdx.x >> 5;
    const int s0 = (blockIdx.x & 31) * 16;
    const int j = 16 * w + l16;

    // B-fragments of Wk for this wave's j: bk16[kt][jj] = Wk[32kt+8q+jj][j]
    f16x8 bk16[8];
#pragma unroll
    for (int kt = 0; kt < 8; kt++) {
        f16x8 v;
#pragma unroll
        for (int jj = 0; jj < 8; jj++)
            v[jj] = (_Float16)Wk[(32 * kt + 8 * q + jj) * Hh + j];
        bk16[kt] = v;
    }
    const float qj = qtot[(size_t)b * Hh + j];
    const float wej = We[j];

    // A-fragments straight from global (L1 absorbs the 8x wave redundancy)
    const _Float16* arow = hs16 + ((size_t)b * Ss + s0 + l16) * (2 * Hh) + 8 * q;
    f32x4 acc = {0.f, 0.f, 0.f, 0.f};
#pragma unroll
    for (int kt = 0; kt < 8; kt++) {
        const f16x8 a = *(const f16x8*)(arow + 32 * kt);
        acc = __builtin_amdgcn_mfma_f32_16x16x32_f16(a, bk16[kt], acc, 0, 0, 0);
    }
    float vals[4];
#pragma unroll
    for (int r = 0; r < 4; r++) {
        float x = acc[r] + qj;
        x = fminf(fmaxf(x, -15.0f), 15.0f);
        const float e = __expf(-2.0f * x);
        vals[r] = (1.0f - e) * rcpf(1.0f + e) * wej;
    }
    // reduce over the 16 j-lanes (l16)
#pragma unroll
    for (int m = 1; m < 16; m <<= 1) {
#pragma unroll
        for (int r = 0; r < 4; r++) vals[r] += __shfl_xor(vals[r], m);
    }
    if (l16 == 0) {
#pragma unroll
        for (int r = 0; r < 4; r++) redl[w * 16 + 4 * q + r] = vals[r];
    }
    __syncthreads();
    if (tid < 16) {
        float e = 0.0f;
#pragma unroll
        for (int ww = 0; ww < 8; ww++) e += redl[ww * 16 + tid];
        energy[(size_t)b * Ss + s0 + tid] = e;
    }
}

// ---------------- Kernel 5: masked softmax over S + weighted context ----------------
__global__ void __launch_bounds__(256)
ctx_kernel(const float* __restrict__ energy, const float* __restrict__ maskf,
           const _Float16* __restrict__ hs16, float* __restrict__ outp)
{
    __shared__ __align__(16) float w[Ss];
    __shared__ float redm[4], reds[4];
    int b = blockIdx.x, tid = threadIdx.x;

    float e0 = energy[(size_t)b * Ss + tid];
    float e1 = energy[(size_t)b * Ss + tid + 256];
    float m0 = maskf[(size_t)b * Ss + tid];
    float m1 = maskf[(size_t)b * Ss + tid + 256];
    e0 += (1.0f - m0) * -1e9f;
    e1 += (1.0f - m1) * -1e9f;

    float mx = fmaxf(e0, e1);
#pragma unroll
    for (int off = 32; off > 0; off >>= 1) mx = fmaxf(mx, __shfl_down(mx, off));
    if ((tid & 63) == 0) redm[tid >> 6] = mx;
    __syncthreads();
    mx = fmaxf(fmaxf(redm[0], redm[1]), fmaxf(redm[2], redm[3]));

    float p0 = __expf(e0 - mx), p1 = __expf(e1 - mx);
    float sm = p0 + p1;
#pragma unroll
    for (int off = 32; off > 0; off >>= 1) sm += __shfl_down(sm, off);
    if ((tid & 63) == 0) reds[tid >> 6] = sm;
    __syncthreads();
    sm = reds[0] + reds[1] + reds[2] + reds[3];
    float inv = rcpf(sm);
    w[tid] = p0 * inv;
    w[tid + 256] = p1 * inv;
    __syncthreads();

    float ctx = 0.0f;
    const _Float16* hsb = hs16 + (size_t)b * Ss * (2 * Hh) + tid;
    const float4* w4 = (const float4*)w;
#pragma unroll 4
    for (int s4i = 0; s4i < Ss / 4; s4i++) {
        float4 ww = w4[s4i];
        size_t base = (size_t)(s4i * 4) * (2 * Hh);
        ctx += ww.x * (float)hsb[base];
        ctx += ww.y * (float)hsb[base + 256];
        ctx += ww.z * (float)hsb[base + 512];
        ctx += ww.w * (float)hsb[base + 768];
    }
    outp[(size_t)b * (2 * Hh) + tid] = ctx;
}

// ---------------- Launcher ----------------
extern "C" void kernel_launch(void* const* d_in, const int* in_sizes, int n_in,
                              void* d_out, int out_size, void* d_ws, size_t ws_size,
                              hipStream_t stream) {
    const int*   tags  = (const int*)d_in[0];
    const float* skips = (const float*)d_in[1];
    const float* table = (const float*)d_in[2];
    const float* Kf    = (const float*)d_in[3];
    const float* Rf    = (const float*)d_in[4];
    const float* Skf   = (const float*)d_in[5];
    const float* bf    = (const float*)d_in[6];
    const float* Kb    = (const float*)d_in[7];
    const float* Rb    = (const float*)d_in[8];
    const float* Skb   = (const float*)d_in[9];
    const float* bb    = (const float*)d_in[10];
    const float* Wk    = (const float*)d_in[11];
    const float* bk    = (const float*)d_in[12];
    const float* Wq    = (const float*)d_in[13];
    const float* bq    = (const float*)d_in[14];
    const float* We    = (const float*)d_in[15];

    char* ws = (char*)d_ws;
    _Float16* gru16   = (_Float16*)ws; ws += (size_t)BSn * 32 * 2;      // 8.4 MB
    _Float16* skips16 = (_Float16*)ws; ws += (size_t)BSn * SKIPn * 2;   // 16.8 MB
    float* maskf  = (float*)ws;  ws += (size_t)BSn * 4;                 // 0.5 MB  [b][t]
    float* maskt  = (float*)ws;  ws += (size_t)BSn * 4;                 // 0.5 MB  [t][b]
    _Float16* hs16 = (_Float16*)ws; ws += (size_t)BSn * 2 * Hh * 2;     // 67.1 MB
    float* hfwd   = (float*)ws;  ws += (size_t)Bb * Hh * 4;
    float* qtot   = (float*)ws;  ws += (size_t)Bb * Hh * 4;
    float* energy = (float*)ws;  ws += (size_t)BSn * 4;                 // total ~94 MB

    pool_kernel<<<BSn / 8, 256, 0, stream>>>(tags, table, gru16, maskf, maskt);
    cvt_kernel<<<BSn * SKIPn / (256 * 8), 256, 0, stream>>>(skips, skips16);
    scan_kernel<<<32, 512, 0, stream>>>(gru16, skips16, maskt,
                                        Kf, Rf, Skf, bf,
                                        Kb, Rb, Skb, bb,
                                        hs16, hfwd);
    q_kernel<<<Bb, Hh, 0, stream>>>(hfwd, Wq, bq, bk, qtot);
    energy_kernel<<<Bb * 32, 512, 0, stream>>>(hs16, qtot, Wk, We, energy);
    ctx_kernel<<<Bb, 256, 0, stream>>>(energy, maskf, hs16, (float*)d_out);
}

// Round 7
// 651.573 us; speedup vs baseline: 3.8749x; 1.3594x over previous
//
#include <hip/hip_runtime.h>
#include <math.h>

#define Bb 256
#define Ss 512
#define Tt 20
#define Ee 25
#define Hh 128
#define SKIPn 64
#define H4n 512
#define BSn (Bb*Ss)
#define MG 4             // batch rows per scan block (replicated 4x in M)
#define HP 136           // h16 LDS row pitch in halves (128 + 8 pad)
#define LOG2E 1.4426950408889634f

typedef _Float16 f16x8 __attribute__((ext_vector_type(8)));
typedef float f32x4 __attribute__((ext_vector_type(4)));

__device__ __forceinline__ float rcpf(float x) { return __builtin_amdgcn_rcpf(x); }
__device__ __forceinline__ float exp2f_(float x) { return __builtin_amdgcn_exp2f(x); }

// Barrier that waits only on LDS ops (lgkmcnt(0)); leaves vmcnt in flight.
__device__ __forceinline__ void lgkm_barrier() {
    __asm__ __volatile__("" ::: "memory");
    __builtin_amdgcn_s_waitcnt(0xC07F);
    __builtin_amdgcn_s_barrier();
    __asm__ __volatile__("" ::: "memory");
}

// ---------------- Kernel 1: embedding mean-pool (fp16 out, [t][b][32]) + masks ----------------
__global__ void pool_kernel(const int* __restrict__ tags,
                            const float* __restrict__ table,
                            _Float16* __restrict__ gru16, float* __restrict__ maskf,
                            float* __restrict__ maskt) {
    int group = blockIdx.x * 8 + (threadIdx.x >> 5);
    int lane = threadIdx.x & 31;
    if (group >= BSn) return;
    int b = group >> 9;          // group = b*Ss + t
    int t = group & (Ss - 1);
    const int* tg = tags + (size_t)group * Tt;
    float acc = 0.0f;
    int cnt = 0;
    int first = tg[0];
#pragma unroll
    for (int tt = 0; tt < Tt; tt++) {
        int tag = tg[tt];
        if (tag != 0) {
            cnt++;
            if (lane < Ee) acc += table[(size_t)tag * Ee + lane];
        }
    }
    float scale = rcpf((float)(cnt > 0 ? cnt : 1));
    float v = (lane < Ee) ? acc * scale : 0.0f;
    gru16[((size_t)t * Bb + b) * 32 + lane] = (_Float16)v;
    if (lane == 0) {
        float m = (first != 0) ? 1.0f : 0.0f;
        maskf[group] = m;                       // [b][t] for ctx
        maskt[(size_t)t * Bb + b] = m;          // [t][b] for scan
    }
}

// ---------------- Kernel 1b: skips fp32 -> fp16 flat copy ----------------
__global__ void __launch_bounds__(256)
cvt_kernel(const float* __restrict__ in, _Float16* __restrict__ out) {
    size_t i = ((size_t)blockIdx.x * 256 + threadIdx.x) * 8;
    f32x4 a = *(const f32x4*)(in + i);
    f32x4 b = *(const f32x4*)(in + i + 4);
    f16x8 o;
#pragma unroll
    for (int j = 0; j < 4; j++) { o[j] = (_Float16)a[j]; o[j + 4] = (_Float16)b[j]; }
    *(f16x8*)(out + i) = o;
}

// ---------------- Kernel 2: bidirectional LSTM scan via MFMA fp16, MG=4 replicated ----------------
// Grid = 128 blocks (2 dir x 64 batch-groups of 4), 512 threads = 8 waves.
// A rows = 4*batch + replica (4 replicas) -> C row 4q+r == batch q for all r:
// every lane owns all 4 gate-z of ONE cell (batch q, col 16w+l16) in regs.
// Weights pre-scaled by log2e (2*log2e for g-gate) -> gates use raw exp2.
__global__ void __launch_bounds__(512)
__attribute__((amdgpu_waves_per_eu(2, 2)))
scan_kernel(const _Float16* __restrict__ gru16, const _Float16* __restrict__ skips16,
            const float* __restrict__ maskt,
            const float* __restrict__ Kf, const float* __restrict__ Rf,
            const float* __restrict__ Skf, const float* __restrict__ bf,
            const float* __restrict__ Kb, const float* __restrict__ Rb,
            const float* __restrict__ Skb, const float* __restrict__ bb,
            _Float16* __restrict__ hs16, float* __restrict__ hfwd)
{
    __shared__ __align__(16) _Float16 h16[2 * MG * HP];

    const int tid = threadIdx.x;
    const int lane = tid & 63;
    const int w = tid >> 6;
    const int l16 = lane & 15;
    const int q = lane >> 4;         // this thread's batch row (0..3)
    const int mb = l16 >> 2;         // A-fragment source batch row (replicated)
    const int bg = blockIdx.x & 63;
    const int dir = blockIdx.x >> 6;
    const int b0 = bg * MG;
    const int col = 16 * w + l16;    // this thread's h column

    const float* Kw = dir ? Kb : Kf;
    const float* Rw = dir ? Rb : Rf;
    const float* Sw = dir ? Skb : Skf;
    const float* bw = dir ? bb : bf;

    // per-gate exp2 folding scale: sigmoid gates *log2e, tanh gate *2log2e
    const float gs[4] = {LOG2E, LOG2E, 2.0f * LOG2E, LOG2E};

    // B-fragments, gate-interleaved+scaled: bfr[kt][g][j] = gs[g]*W[32kt+8q+j][g*128+col]
    f16x8 bfr[7][4];
#pragma unroll
    for (int kt = 0; kt < 7; kt++) {
#pragma unroll
        for (int g = 0; g < 4; g++) {
            const int n = g * Hh + col;
            f16x8 v;
#pragma unroll
            for (int j = 0; j < 8; j++) {
                const int k = 32 * kt + 8 * q + j;
                float x;
                if (k < 32)        x = (k < Ee) ? Kw[k * H4n + n] : 0.0f;
                else if (k < 160)  x = Rw[(k - 32) * H4n + n];
                else               x = Sw[(k - 160) * H4n + n];
                v[j] = (_Float16)(x * gs[g]);
            }
            bfr[kt][g] = v;
        }
    }
    float biasv[4];
#pragma unroll
    for (int g = 0; g < 4; g++) biasv[g] = bw[g * Hh + col] * gs[g];

    for (int idx = tid; idx < 2 * MG * HP; idx += 512) h16[idx] = (_Float16)0.0f;

    const _Float16* srow = skips16 + (size_t)(b0 + mb) * Ss * SKIPn;
    float c = 0.0f, h = 0.0f;

    // hs16 offset in halves; per-step delta +-256
    unsigned off = ((unsigned)(b0 + q) * Ss + (dir ? Ss - 1 : 0)) * (2 * Hh) + dir * Hh + col;
    const int odelta = dir ? -(2 * Hh) : (2 * Hh);

    // 2-slot depth-2 prefetch
    f16x8 xA, xB, sA0, sA1, sB0, sB1;
    float mA, mB;
    auto issue = [&](f16x8& xf, f16x8& s0, f16x8& s1, float& mk, int i) {
        const int ii = (i < Ss) ? i : (Ss - 1);
        const int t = dir ? (Ss - 1 - ii) : ii;
        xf = *(const f16x8*)(gru16 + ((size_t)t * Bb + b0 + mb) * 32 + 8 * q);
        const _Float16* sp = srow + (size_t)t * SKIPn;
        s0 = *(const f16x8*)(sp + 8 * q);
        s1 = *(const f16x8*)(sp + 32 + 8 * q);
        mk = maskt[(size_t)t * Bb + b0 + q];
    };
    issue(xA, sA0, sA1, mA, 0);
    issue(xB, sB0, sB1, mB, 1);
    __syncthreads();

    auto body = [&](int i, f16x8& xf, f16x8& s0, f16x8& s1, float& mkv) {
        const f16x8 ax = xf, as0 = s0, as1 = s1;
        const float mk = mkv;
        issue(xf, s0, s1, mkv, i + 2);   // refill for step i+2

        f32x4 acc[4];
#pragma unroll
        for (int g = 0; g < 4; g++) {
            f32x4 a = {biasv[g], biasv[g], biasv[g], biasv[g]};
            acc[g] = a;
        }
#pragma unroll
        for (int g = 0; g < 4; g++) {
            acc[g] = __builtin_amdgcn_mfma_f32_16x16x32_f16(ax,  bfr[0][g], acc[g], 0, 0, 0);
            acc[g] = __builtin_amdgcn_mfma_f32_16x16x32_f16(as0, bfr[5][g], acc[g], 0, 0, 0);
            acc[g] = __builtin_amdgcn_mfma_f32_16x16x32_f16(as1, bfr[6][g], acc[g], 0, 0, 0);
        }
        const _Float16* hb = h16 + (i & 1) * (MG * HP);
#pragma unroll
        for (int kt = 0; kt < 4; kt++) {
            const f16x8 ah = *(const f16x8*)(hb + mb * HP + 32 * kt + 8 * q);
#pragma unroll
            for (int g = 0; g < 4; g++)
                acc[g] = __builtin_amdgcn_mfma_f32_16x16x32_f16(ah, bfr[1 + kt][g], acc[g], 0, 0, 0);
        }

        // ---- gates: 1 cell/thread (batch q, col), replicas identical -> use [0]
        const float zi = acc[0][0], zf = acc[1][0], zg = acc[2][0], zo = acc[3][0];
        const float ei = exp2f_(fminf(-zi, 88.0f));   // e^{-z_i}
        const float ef = exp2f_(fminf(-zf, 88.0f));
        const float eg = exp2f_(fminf(-zg, 88.0f));   // e^{-2 z_g}
        const float eo = exp2f_(fminf(-zo, 88.0f));
        const float pi = 1.0f + ei, pg = 1.0f + eg, pf = 1.0f + ef;
        const float p  = pi * pg;
        const float t1 = (1.0f - eg) * pf;
        const float cn = fmaf(c, p, t1) * rcpf(pf * p);
        const float ec = exp2f_(fminf(cn * (-2.0f * LOG2E), 88.0f));   // e^{-2 cn}
        const float hn = (1.0f - ec) * rcpf((1.0f + eo) * (1.0f + ec));
        const bool mm = (mk != 0.0f);
        c = mm ? cn : c;
        h = mm ? hn : h;

        _Float16* hw = h16 + ((i + 1) & 1) * (MG * HP);
        hw[q * HP + col] = (_Float16)h;
        hs16[off] = (_Float16)h;
        off += odelta;
        lgkm_barrier();
    };

#pragma unroll 1
    for (int i = 0; i < Ss; i += 2) {
        body(i,     xA, sA0, sA1, mA);
        body(i + 1, xB, sB0, sB1, mB);
    }

    if (dir == 0) hfwd[(size_t)(b0 + q) * Hh + col] = h;
}

// ---------------- Kernel 3: qtot = h_fwd @ Wq + bq + bk ----------------
__global__ void q_kernel(const float* __restrict__ hfwd, const float* __restrict__ Wq,
                         const float* __restrict__ bq, const float* __restrict__ bk,
                         float* __restrict__ qtot) {
    __shared__ float hl[Hh];
    int b = blockIdx.x, j = threadIdx.x;
    hl[j] = hfwd[(size_t)b * Hh + j];
    __syncthreads();
    float q = bq[j] + bk[j];
#pragma unroll
    for (int k = 0; k < Hh; k++) q += hl[k] * Wq[k * Hh + j];
    qtot[(size_t)b * Hh + j] = q;
}

// ---------------- Kernel 4: energy via MFMA: tanh(out@Wk + qtot) @ We ----------------
// Grid = Bb * 32 blocks (16 s-rows each), 512 threads; wave w owns j-tile w.
__global__ void __launch_bounds__(512)
energy_kernel(const _Float16* __restrict__ hs16, const float* __restrict__ qtot,
              const float* __restrict__ Wk, const float* __restrict__ We,
              float* __restrict__ energy)
{
    __shared__ float redl[8 * 16];
    const int tid = threadIdx.x;
    const int lane = tid & 63;
    const int w = tid >> 6;
    const int l16 = lane & 15;
    const int q = lane >> 4;
    const int b = blockIdx.x >> 5;
    const int s0 = (blockIdx.x & 31) * 16;
    const int j = 16 * w + l16;

    // B-fragments of Wk for this wave's j: bk16[kt][jj] = Wk[32kt+8q+jj][j]
    f16x8 bk16[8];
#pragma unroll
    for (int kt = 0; kt < 8; kt++) {
        f16x8 v;
#pragma unroll
        for (int jj = 0; jj < 8; jj++)
            v[jj] = (_Float16)Wk[(32 * kt + 8 * q + jj) * Hh + j];
        bk16[kt] = v;
    }
    const float qj = qtot[(size_t)b * Hh + j];
    const float wej = We[j];

    // A-fragments straight from global (L1 absorbs the 8x wave redundancy)
    const _Float16* arow = hs16 + ((size_t)b * Ss + s0 + l16) * (2 * Hh) + 8 * q;
    f32x4 acc = {0.f, 0.f, 0.f, 0.f};
#pragma unroll
    for (int kt = 0; kt < 8; kt++) {
        const f16x8 a = *(const f16x8*)(arow + 32 * kt);
        acc = __builtin_amdgcn_mfma_f32_16x16x32_f16(a, bk16[kt], acc, 0, 0, 0);
    }
    float vals[4];
#pragma unroll
    for (int r = 0; r < 4; r++) {
        float x = acc[r] + qj;
        x = fminf(fmaxf(x, -15.0f), 15.0f);
        const float e = __expf(-2.0f * x);
        vals[r] = (1.0f - e) * rcpf(1.0f + e) * wej;
    }
    // reduce over the 16 j-lanes (l16)
#pragma unroll
    for (int m = 1; m < 16; m <<= 1) {
#pragma unroll
        for (int r = 0; r < 4; r++) vals[r] += __shfl_xor(vals[r], m);
    }
    if (l16 == 0) {
#pragma unroll
        for (int r = 0; r < 4; r++) redl[w * 16 + 4 * q + r] = vals[r];
    }
    __syncthreads();
    if (tid < 16) {
        float e = 0.0f;
#pragma unroll
        for (int ww = 0; ww < 8; ww++) e += redl[ww * 16 + tid];
        energy[(size_t)b * Ss + s0 + tid] = e;
    }
}

// ---------------- Kernel 5: masked softmax over S + weighted context ----------------
__global__ void __launch_bounds__(256)
ctx_kernel(const float* __restrict__ energy, const float* __restrict__ maskf,
           const _Float16* __restrict__ hs16, float* __restrict__ outp)
{
    __shared__ __align__(16) float w[Ss];
    __shared__ float redm[4], reds[4];
    int b = blockIdx.x, tid = threadIdx.x;

    float e0 = energy[(size_t)b * Ss + tid];
    float e1 = energy[(size_t)b * Ss + tid + 256];
    float m0 = maskf[(size_t)b * Ss + tid];
    float m1 = maskf[(size_t)b * Ss + tid + 256];
    e0 += (1.0f - m0) * -1e9f;
    e1 += (1.0f - m1) * -1e9f;

    float mx = fmaxf(e0, e1);
#pragma unroll
    for (int off = 32; off > 0; off >>= 1) mx = fmaxf(mx, __shfl_down(mx, off));
    if ((tid & 63) == 0) redm[tid >> 6] = mx;
    __syncthreads();
    mx = fmaxf(fmaxf(redm[0], redm[1]), fmaxf(redm[2], redm[3]));

    float p0 = __expf(e0 - mx), p1 = __expf(e1 - mx);
    float sm = p0 + p1;
#pragma unroll
    for (int off = 32; off > 0; off >>= 1) sm += __shfl_down(sm, off);
    if ((tid & 63) == 0) reds[tid >> 6] = sm;
    __syncthreads();
    sm = reds[0] + reds[1] + reds[2] + reds[3];
    float inv = rcpf(sm);
    w[tid] = p0 * inv;
    w[tid + 256] = p1 * inv;
    __syncthreads();

    float ctx = 0.0f;
    const _Float16* hsb = hs16 + (size_t)b * Ss * (2 * Hh) + tid;
    const float4* w4 = (const float4*)w;
#pragma unroll 4
    for (int s4i = 0; s4i < Ss / 4; s4i++) {
        float4 ww = w4[s4i];
        size_t base = (size_t)(s4i * 4) * (2 * Hh);
        ctx += ww.x * (float)hsb[base];
        ctx += ww.y * (float)hsb[base + 256];
        ctx += ww.z * (float)hsb[base + 512];
        ctx += ww.w * (float)hsb[base + 768];
    }
    outp[(size_t)b * (2 * Hh) + tid] = ctx;
}

// ---------------- Launcher ----------------
extern "C" void kernel_launch(void* const* d_in, const int* in_sizes, int n_in,
                              void* d_out, int out_size, void* d_ws, size_t ws_size,
                              hipStream_t stream) {
    const int*   tags  = (const int*)d_in[0];
    const float* skips = (const float*)d_in[1];
    const float* table = (const float*)d_in[2];
    const float* Kf    = (const float*)d_in[3];
    const float* Rf    = (const float*)d_in[4];
    const float* Skf   = (const float*)d_in[5];
    const float* bf    = (const float*)d_in[6];
    const float* Kb    = (const float*)d_in[7];
    const float* Rb    = (const float*)d_in[8];
    const float* Skb   = (const float*)d_in[9];
    const float* bb    = (const float*)d_in[10];
    const float* Wk    = (const float*)d_in[11];
    const float* bk    = (const float*)d_in[12];
    const float* Wq    = (const float*)d_in[13];
    const float* bq    = (const float*)d_in[14];
    const float* We    = (const float*)d_in[15];

    char* ws = (char*)d_ws;
    _Float16* gru16   = (_Float16*)ws; ws += (size_t)BSn * 32 * 2;      // 8.4 MB
    _Float16* skips16 = (_Float16*)ws; ws += (size_t)BSn * SKIPn * 2;   // 16.8 MB
    float* maskf  = (float*)ws;  ws += (size_t)BSn * 4;                 // 0.5 MB  [b][t]
    float* maskt  = (float*)ws;  ws += (size_t)BSn * 4;                 // 0.5 MB  [t][b]
    _Float16* hs16 = (_Float16*)ws; ws += (size_t)BSn * 2 * Hh * 2;     // 67.1 MB
    float* hfwd   = (float*)ws;  ws += (size_t)Bb * Hh * 4;
    float* qtot   = (float*)ws;  ws += (size_t)Bb * Hh * 4;
    float* energy = (float*)ws;  ws += (size_t)BSn * 4;                 // total ~94 MB

    pool_kernel<<<BSn / 8, 256, 0, stream>>>(tags, table, gru16, maskf, maskt);
    cvt_kernel<<<BSn * SKIPn / (256 * 8), 256, 0, stream>>>(skips, skips16);
    scan_kernel<<<128, 512, 0, stream>>>(gru16, skips16, maskt,
                                         Kf, Rf, Skf, bf,
                                         Kb, Rb, Skb, bb,
                                         hs16, hfwd);
    q_kernel<<<Bb, Hh, 0, stream>>>(hfwd, Wq, bq, bk, qtot);
    energy_kernel<<<Bb * 32, 512, 0, stream>>>(hs16, qtot, Wk, We, energy);
    ctx_kernel<<<Bb, 256, 0, stream>>>(energy, maskf, hs16, (float*)d_out);
}

// Round 8
// 608.836 us; speedup vs baseline: 4.1468x; 1.0702x over previous
//
#include <hip/hip_runtime.h>
#include <math.h>

#define Bb 256
#define Ss 512
#define Tt 20
#define Ee 25
#define Hh 128
#define SKIPn 64
#define H4n 512
#define BSn (Bb*Ss)
#define MG 4             // batch rows per scan block (replicated 4x in M)
#define HP 160           // h16 LDS row pitch in halves: 80 words == 16 mod 32 -> free 2-way
#define LOG2E 1.4426950408889634f

typedef _Float16 f16x8 __attribute__((ext_vector_type(8)));
typedef float f32x4 __attribute__((ext_vector_type(4)));

__device__ __forceinline__ float rcpf(float x) { return __builtin_amdgcn_rcpf(x); }
__device__ __forceinline__ float exp2f_(float x) { return __builtin_amdgcn_exp2f(x); }

// Barrier that waits only on LDS ops (lgkmcnt(0)); leaves vmcnt in flight.
__device__ __forceinline__ void lgkm_barrier() {
    __asm__ __volatile__("" ::: "memory");
    __builtin_amdgcn_s_waitcnt(0xC07F);
    __builtin_amdgcn_s_barrier();
    __asm__ __volatile__("" ::: "memory");
}

// ---------------- Kernel 1: embedding mean-pool (fp16 out, [t][b][32]) + masks ----------------
__global__ void pool_kernel(const int* __restrict__ tags,
                            const float* __restrict__ table,
                            _Float16* __restrict__ gru16, float* __restrict__ maskf,
                            float* __restrict__ maskt) {
    int group = blockIdx.x * 8 + (threadIdx.x >> 5);
    int lane = threadIdx.x & 31;
    if (group >= BSn) return;
    int b = group >> 9;          // group = b*Ss + t
    int t = group & (Ss - 1);
    const int* tg = tags + (size_t)group * Tt;
    float acc = 0.0f;
    int cnt = 0;
    int first = tg[0];
#pragma unroll
    for (int tt = 0; tt < Tt; tt++) {
        int tag = tg[tt];
        if (tag != 0) {
            cnt++;
            if (lane < Ee) acc += table[(size_t)tag * Ee + lane];
        }
    }
    float scale = rcpf((float)(cnt > 0 ? cnt : 1));
    float v = (lane < Ee) ? acc * scale : 0.0f;
    gru16[((size_t)t * Bb + b) * 32 + lane] = (_Float16)v;
    if (lane == 0) {
        float m = (first != 0) ? 1.0f : 0.0f;
        maskf[group] = m;                       // [b][t] for attn
        maskt[(size_t)t * Bb + b] = m;          // [t][b] for scan
    }
}

// ---------------- Kernel 1b: skips fp32 -> fp16 flat copy ----------------
__global__ void __launch_bounds__(256)
cvt_kernel(const float* __restrict__ in, _Float16* __restrict__ out) {
    size_t i = ((size_t)blockIdx.x * 256 + threadIdx.x) * 8;
    f32x4 a = *(const f32x4*)(in + i);
    f32x4 b = *(const f32x4*)(in + i + 4);
    f16x8 o;
#pragma unroll
    for (int j = 0; j < 4; j++) { o[j] = (_Float16)a[j]; o[j + 4] = (_Float16)b[j]; }
    *(f16x8*)(out + i) = o;
}

// ---------------- Kernel 2: bidirectional LSTM scan via MFMA fp16, MG=4 replicated ----------------
// Grid = 128 blocks (2 dir x 64 batch-groups of 4), 512 threads = 8 waves.
// A rows = 4*batch + replica -> every lane owns all 4 gate-z of ONE cell.
// R8: HP=160 (conflict-free h reads); slot refill AFTER MFMA use (no copies);
// h ds_reads hoisted above x/s MFMAs (latency hidden).
__global__ void __launch_bounds__(512)
__attribute__((amdgpu_waves_per_eu(2, 2)))
scan_kernel(const _Float16* __restrict__ gru16, const _Float16* __restrict__ skips16,
            const float* __restrict__ maskt,
            const float* __restrict__ Kf, const float* __restrict__ Rf,
            const float* __restrict__ Skf, const float* __restrict__ bf,
            const float* __restrict__ Kb, const float* __restrict__ Rb,
            const float* __restrict__ Skb, const float* __restrict__ bb,
            _Float16* __restrict__ hs16, float* __restrict__ hfwd)
{
    __shared__ __align__(16) _Float16 h16[2 * MG * HP];

    const int tid = threadIdx.x;
    const int lane = tid & 63;
    const int w = tid >> 6;
    const int l16 = lane & 15;
    const int q = lane >> 4;         // this thread's batch row (0..3)
    const int mb = l16 >> 2;         // A-fragment source batch row (replicated)
    const int bg = blockIdx.x & 63;
    const int dir = blockIdx.x >> 6;
    const int b0 = bg * MG;
    const int col = 16 * w + l16;    // this thread's h column

    const float* Kw = dir ? Kb : Kf;
    const float* Rw = dir ? Rb : Rf;
    const float* Sw = dir ? Skb : Skf;
    const float* bw = dir ? bb : bf;

    // per-gate exp2 folding scale: sigmoid gates *log2e, tanh gate *2log2e
    const float gs[4] = {LOG2E, LOG2E, 2.0f * LOG2E, LOG2E};

    // B-fragments, gate-interleaved+scaled: bfr[kt][g][j] = gs[g]*W[32kt+8q+j][g*128+col]
    f16x8 bfr[7][4];
#pragma unroll
    for (int kt = 0; kt < 7; kt++) {
#pragma unroll
        for (int g = 0; g < 4; g++) {
            const int n = g * Hh + col;
            f16x8 v;
#pragma unroll
            for (int j = 0; j < 8; j++) {
                const int k = 32 * kt + 8 * q + j;
                float x;
                if (k < 32)        x = (k < Ee) ? Kw[k * H4n + n] : 0.0f;
                else if (k < 160)  x = Rw[(k - 32) * H4n + n];
                else               x = Sw[(k - 160) * H4n + n];
                v[j] = (_Float16)(x * gs[g]);
            }
            bfr[kt][g] = v;
        }
    }
    float biasv[4];
#pragma unroll
    for (int g = 0; g < 4; g++) biasv[g] = bw[g * Hh + col] * gs[g];

    for (int idx = tid; idx < 2 * MG * HP; idx += 512) h16[idx] = (_Float16)0.0f;

    const _Float16* srow = skips16 + (size_t)(b0 + mb) * Ss * SKIPn;
    float c = 0.0f, h = 0.0f;

    // hs16 offset in halves; per-step delta +-256
    unsigned off = ((unsigned)(b0 + q) * Ss + (dir ? Ss - 1 : 0)) * (2 * Hh) + dir * Hh + col;
    const int odelta = dir ? -(2 * Hh) : (2 * Hh);

    auto issue_xs = [&](f16x8& xf, f16x8& s0, f16x8& s1, int i) {
        const int ii = (i < Ss) ? i : (Ss - 1);
        const int t = dir ? (Ss - 1 - ii) : ii;
        xf = *(const f16x8*)(gru16 + ((size_t)t * Bb + b0 + mb) * 32 + 8 * q);
        const _Float16* sp = srow + (size_t)t * SKIPn;
        s0 = *(const f16x8*)(sp + 8 * q);
        s1 = *(const f16x8*)(sp + 32 + 8 * q);
    };
    auto issue_m = [&](float& mk, int i) {
        const int ii = (i < Ss) ? i : (Ss - 1);
        const int t = dir ? (Ss - 1 - ii) : ii;
        mk = maskt[(size_t)t * Bb + b0 + q];
    };

    // 2-slot depth-2 prefetch
    f16x8 xA, xB, sA0, sA1, sB0, sB1;
    float mA, mB;
    issue_xs(xA, sA0, sA1, 0); issue_m(mA, 0);
    issue_xs(xB, sB0, sB1, 1); issue_m(mB, 1);
    __syncthreads();

    auto body = [&](int i, f16x8& xf, f16x8& s0, f16x8& s1, float& mkv) {
        // h fragments first: ds latency hides under the x/s MFMAs
        const _Float16* hb = h16 + (i & 1) * (MG * HP);
        const f16x8 ah0 = *(const f16x8*)(hb + mb * HP +  0 + 8 * q);
        const f16x8 ah1 = *(const f16x8*)(hb + mb * HP + 32 + 8 * q);
        const f16x8 ah2 = *(const f16x8*)(hb + mb * HP + 64 + 8 * q);
        const f16x8 ah3 = *(const f16x8*)(hb + mb * HP + 96 + 8 * q);

        f32x4 acc[4];
#pragma unroll
        for (int g = 0; g < 4; g++) {
            f32x4 a = {biasv[g], biasv[g], biasv[g], biasv[g]};
            acc[g] = a;
        }
#pragma unroll
        for (int g = 0; g < 4; g++) {
            acc[g] = __builtin_amdgcn_mfma_f32_16x16x32_f16(xf, bfr[0][g], acc[g], 0, 0, 0);
            acc[g] = __builtin_amdgcn_mfma_f32_16x16x32_f16(s0, bfr[5][g], acc[g], 0, 0, 0);
            acc[g] = __builtin_amdgcn_mfma_f32_16x16x32_f16(s1, bfr[6][g], acc[g], 0, 0, 0);
        }
        // refill x/s for step i+2 AFTER their last use (no fragment copies)
        issue_xs(xf, s0, s1, i + 2);
#pragma unroll
        for (int g = 0; g < 4; g++) {
            acc[g] = __builtin_amdgcn_mfma_f32_16x16x32_f16(ah0, bfr[1][g], acc[g], 0, 0, 0);
            acc[g] = __builtin_amdgcn_mfma_f32_16x16x32_f16(ah1, bfr[2][g], acc[g], 0, 0, 0);
            acc[g] = __builtin_amdgcn_mfma_f32_16x16x32_f16(ah2, bfr[3][g], acc[g], 0, 0, 0);
            acc[g] = __builtin_amdgcn_mfma_f32_16x16x32_f16(ah3, bfr[4][g], acc[g], 0, 0, 0);
        }

        // ---- gates: 1 cell/thread (batch q, col)
        const float mk = mkv;
        issue_m(mkv, i + 2);
        const float zi = acc[0][0], zf = acc[1][0], zg = acc[2][0], zo = acc[3][0];
        const float ei = exp2f_(fminf(-zi, 88.0f));   // e^{-z_i}
        const float ef = exp2f_(fminf(-zf, 88.0f));
        const float eg = exp2f_(fminf(-zg, 88.0f));   // e^{-2 z_g}
        const float eo = exp2f_(fminf(-zo, 88.0f));
        const float pi = 1.0f + ei, pg = 1.0f + eg, pf = 1.0f + ef;
        const float p  = pi * pg;
        const float t1 = (1.0f - eg) * pf;
        const float cn = fmaf(c, p, t1) * rcpf(pf * p);
        const float ec = exp2f_(fminf(cn * (-2.0f * LOG2E), 88.0f));   // e^{-2 cn}
        const float hn = (1.0f - ec) * rcpf((1.0f + eo) * (1.0f + ec));
        const bool mm = (mk != 0.0f);
        c = mm ? cn : c;
        h = mm ? hn : h;

        _Float16* hw = h16 + ((i + 1) & 1) * (MG * HP);
        hw[q * HP + col] = (_Float16)h;
        hs16[off] = (_Float16)h;
        off += odelta;
        lgkm_barrier();
    };

#pragma unroll 1
    for (int i = 0; i < Ss; i += 2) {
        body(i,     xA, sA0, sA1, mA);
        body(i + 1, xB, sB0, sB1, mB);
    }

    if (dir == 0) hfwd[(size_t)(b0 + q) * Hh + col] = h;
}

// ---------------- Kernel 3: fused attention: q + energy + softmax + context ----------------
// Grid = 256 blocks (1 per batch), 512 threads = 8 waves.
__global__ void __launch_bounds__(512)
attn_kernel(const _Float16* __restrict__ hs16, const float* __restrict__ hfwd,
            const float* __restrict__ Wq, const float* __restrict__ bq,
            const float* __restrict__ bk,
            const float* __restrict__ Wk, const float* __restrict__ We,
            const float* __restrict__ maskf, float* __restrict__ outp)
{
    __shared__ float hfl[Hh];
    __shared__ float qpart[4][Hh];
    __shared__ float qtot_s[Hh];
    __shared__ float epart[8][Ss];      // [wave][s] transposed: conflict-free
    __shared__ float ws2[Ss];           // softmax weights, transposed (s&31)*16+(s>>5)
    __shared__ float redm[8], reds[8];
    __shared__ float ctxp[16][2 * Hh + 1];  // pitch 257: ~2-way max

    const int tid = threadIdx.x;
    const int lane = tid & 63;
    const int w = tid >> 6;
    const int l16 = lane & 15;
    const int q = lane >> 4;
    const int b = blockIdx.x;
    const int j = 16 * w + l16;         // this wave's j-column (0..127)

    // Wk B-fragments (K = 2*Hh = 256): bk16[kt][jj] = Wk[32kt+8q+jj][j]
    f16x8 bk16[8];
#pragma unroll
    for (int kt = 0; kt < 8; kt++) {
        f16x8 v;
#pragma unroll
        for (int jj = 0; jj < 8; jj++)
            v[jj] = (_Float16)Wk[(32 * kt + 8 * q + jj) * Hh + j];
        bk16[kt] = v;
    }
    const float wej = We[j];

    // ---- phase 0: qtot = hfwd[b] @ Wq + bq + bk
    if (tid < Hh) hfl[tid] = hfwd[(size_t)b * Hh + tid];
    __syncthreads();
    {
        const int jj = tid & 127, seg = tid >> 7;
        float p = 0.0f;
#pragma unroll
        for (int k = 0; k < 32; k++)
            p += hfl[32 * seg + k] * Wq[(32 * seg + k) * Hh + jj];
        qpart[seg][jj] = p;
    }
    __syncthreads();
    if (tid < Hh)
        qtot_s[tid] = qpart[0][tid] + qpart[1][tid] + qpart[2][tid] + qpart[3][tid]
                      + bq[tid] + bk[tid];
    __syncthreads();
    const float qj = qtot_s[j];

    // ---- phase 1: energy partials via MFMA (each wave: all 32 s-tiles, its 16 j)
    const _Float16* hb = hs16 + (size_t)b * Ss * (2 * Hh);
#pragma unroll 1
    for (int st = 0; st < 32; st++) {
        const int s0 = st * 16;
        const _Float16* arow = hb + (size_t)(s0 + l16) * (2 * Hh) + 8 * q;
        f32x4 acc = {0.f, 0.f, 0.f, 0.f};
#pragma unroll
        for (int kt = 0; kt < 8; kt++) {
            const f16x8 a = *(const f16x8*)(arow + 32 * kt);
            acc = __builtin_amdgcn_mfma_f32_16x16x32_f16(a, bk16[kt], acc, 0, 0, 0);
        }
        float vals[4];
#pragma unroll
        for (int r = 0; r < 4; r++) {
            const float x = acc[r] + qj;
            const float e = exp2f_(fminf(x * (-2.0f * LOG2E), 80.0f));
            vals[r] = (1.0f - e) * rcpf(1.0f + e) * wej;   // tanh(x)*We[j]
        }
#pragma unroll
        for (int m = 1; m < 16; m <<= 1) {
#pragma unroll
            for (int r = 0; r < 4; r++) vals[r] += __shfl_xor(vals[r], m);
        }
        if (l16 == 0) {
#pragma unroll
            for (int r = 0; r < 4; r++) epart[w][s0 + 4 * q + r] = vals[r];
        }
    }
    __syncthreads();

    // ---- phase 2: masked softmax over S (thread tid owns s=tid)
    {
        float e = 0.0f;
#pragma unroll
        for (int ww = 0; ww < 8; ww++) e += epart[ww][tid];
        e += (1.0f - maskf[(size_t)b * Ss + tid]) * -1e9f;
        float mx = e;
#pragma unroll
        for (int off = 32; off > 0; off >>= 1) mx = fmaxf(mx, __shfl_xor(mx, off));
        if (lane == 0) redm[w] = mx;
        __syncthreads();
        mx = redm[0];
#pragma unroll
        for (int ww = 1; ww < 8; ww++) mx = fmaxf(mx, redm[ww]);
        const float p = exp2f_((e - mx) * LOG2E);
        float sm = p;
#pragma unroll
        for (int off = 32; off > 0; off >>= 1) sm += __shfl_xor(sm, off);
        if (lane == 0) reds[w] = sm;
        __syncthreads();
        sm = reds[0] + reds[1] + reds[2] + reds[3] + reds[4] + reds[5] + reds[6] + reds[7];
        ws2[(tid & 31) * 16 + (tid >> 5)] = p * rcpf(sm);
    }
    __syncthreads();

    // ---- phase 3: context. thread = (colgrp cg = tid>>4: cols 8cg..8cg+7, seg = tid&15)
    {
        const int cg = tid >> 4;
        const int seg = tid & 15;
        float a[8];
#pragma unroll
        for (int jj = 0; jj < 8; jj++) a[jj] = 0.0f;
#pragma unroll 4
        for (int sg = 0; sg < 32; sg++) {
            const int s = seg * 32 + sg;
            const float wv = ws2[sg * 16 + seg];
            const f16x8 hv = *(const f16x8*)(hb + (size_t)s * (2 * Hh) + 8 * cg);
#pragma unroll
            for (int jj = 0; jj < 8; jj++) a[jj] = fmaf(wv, (float)hv[jj], a[jj]);
        }
#pragma unroll
        for (int jj = 0; jj < 8; jj++) ctxp[seg][8 * cg + jj] = a[jj];
    }
    __syncthreads();
    if (tid < 2 * Hh) {
        float s = 0.0f;
#pragma unroll
        for (int seg = 0; seg < 16; seg++) s += ctxp[seg][tid];
        outp[(size_t)b * (2 * Hh) + tid] = s;
    }
}

// ---------------- Launcher ----------------
extern "C" void kernel_launch(void* const* d_in, const int* in_sizes, int n_in,
                              void* d_out, int out_size, void* d_ws, size_t ws_size,
                              hipStream_t stream) {
    const int*   tags  = (const int*)d_in[0];
    const float* skips = (const float*)d_in[1];
    const float* table = (const float*)d_in[2];
    const float* Kf    = (const float*)d_in[3];
    const float* Rf    = (const float*)d_in[4];
    const float* Skf   = (const float*)d_in[5];
    const float* bf    = (const float*)d_in[6];
    const float* Kb    = (const float*)d_in[7];
    const float* Rb    = (const float*)d_in[8];
    const float* Skb   = (const float*)d_in[9];
    const float* bb    = (const float*)d_in[10];
    const float* Wk    = (const float*)d_in[11];
    const float* bk    = (const float*)d_in[12];
    const float* Wq    = (const float*)d_in[13];
    const float* bq    = (const float*)d_in[14];
    const float* We    = (const float*)d_in[15];

    char* ws = (char*)d_ws;
    _Float16* gru16   = (_Float16*)ws; ws += (size_t)BSn * 32 * 2;      // 8.4 MB
    _Float16* skips16 = (_Float16*)ws; ws += (size_t)BSn * SKIPn * 2;   // 16.8 MB
    float* maskf  = (float*)ws;  ws += (size_t)BSn * 4;                 // 0.5 MB  [b][t]
    float* maskt  = (float*)ws;  ws += (size_t)BSn * 4;                 // 0.5 MB  [t][b]
    _Float16* hs16 = (_Float16*)ws; ws += (size_t)BSn * 2 * Hh * 2;     // 67.1 MB
    float* hfwd   = (float*)ws;  ws += (size_t)Bb * Hh * 4;             // total ~94 MB

    pool_kernel<<<BSn / 8, 256, 0, stream>>>(tags, table, gru16, maskf, maskt);
    cvt_kernel<<<BSn * SKIPn / (256 * 8), 256, 0, stream>>>(skips, skips16);
    scan_kernel<<<128, 512, 0, stream>>>(gru16, skips16, maskt,
                                         Kf, Rf, Skf, bf,
                                         Kb, Rb, Skb, bb,
                                         hs16, hfwd);
    attn_kernel<<<Bb, 512, 0, stream>>>(hs16, hfwd, Wq, bq, bk, Wk, We, maskf,
                                        (float*)d_out);
}

// Round 9
// 554.024 us; speedup vs baseline: 4.5571x; 1.0989x over previous
//
#include <hip/hip_runtime.h>
#include <math.h>

#define Bb 256
#define Ss 512
#define Tt 20
#define Ee 25
#define Hh 128
#define SKIPn 64
#define H4n 512
#define BSn (Bb*Ss)
#define MG 4             // batch rows per scan block (replicated 4x in M)
#define HP 160           // h16 LDS row pitch in halves: 80 words == 16 mod 32 -> free 2-way
#define LOG2E 1.4426950408889634f

typedef _Float16 f16x8 __attribute__((ext_vector_type(8)));
typedef float f32x4 __attribute__((ext_vector_type(4)));

__device__ __forceinline__ float rcpf(float x) { return __builtin_amdgcn_rcpf(x); }
__device__ __forceinline__ float exp2f_(float x) { return __builtin_amdgcn_exp2f(x); }

// Barrier that waits only on LDS ops (lgkmcnt(0)); leaves vmcnt in flight.
__device__ __forceinline__ void lgkm_barrier() {
    __asm__ __volatile__("" ::: "memory");
    __builtin_amdgcn_s_waitcnt(0xC07F);
    __builtin_amdgcn_s_barrier();
    __asm__ __volatile__("" ::: "memory");
}

// ---------------- Kernel 1: embedding mean-pool (fp16 out, [t][b][32]) + masks ----------------
// R9: unconditional independent gathers (20 loads in flight; mask by tag!=0)
// instead of a predicated serial chain.
__global__ void pool_kernel(const int* __restrict__ tags,
                            const float* __restrict__ table,
                            _Float16* __restrict__ gru16, float* __restrict__ maskf,
                            float* __restrict__ maskt) {
    int group = blockIdx.x * 8 + (threadIdx.x >> 5);
    int lane = threadIdx.x & 31;
    if (group >= BSn) return;
    int b = group >> 9;          // group = b*Ss + t
    int t = group & (Ss - 1);
    const int* tg = tags + (size_t)group * Tt;
    const int el = (lane < Ee) ? lane : (Ee - 1);   // lanes 25..31 read a valid dup

    int tagv[Tt];
#pragma unroll
    for (int tt = 0; tt < Tt; tt++) tagv[tt] = tg[tt];

    float vv[Tt];
#pragma unroll
    for (int tt = 0; tt < Tt; tt++)
        vv[tt] = table[(size_t)tagv[tt] * Ee + el];   // independent, unconditional

    float acc = 0.0f;
    int cnt = 0;
#pragma unroll
    for (int tt = 0; tt < Tt; tt++) {
        const bool nz = (tagv[tt] != 0);
        cnt += nz ? 1 : 0;
        acc += nz ? vv[tt] : 0.0f;
    }
    float scale = rcpf((float)(cnt > 0 ? cnt : 1));
    float v = (lane < Ee) ? acc * scale : 0.0f;
    gru16[((size_t)t * Bb + b) * 32 + lane] = (_Float16)v;
    if (lane == 0) {
        float m = (tagv[0] != 0) ? 1.0f : 0.0f;
        maskf[group] = m;                       // [b][t] for attn
        maskt[(size_t)t * Bb + b] = m;          // [t][b] for scan
    }
}

// ---------------- Kernel 1b: skips fp32 -> fp16 flat copy ----------------
__global__ void __launch_bounds__(256)
cvt_kernel(const float* __restrict__ in, _Float16* __restrict__ out) {
    size_t i = ((size_t)blockIdx.x * 256 + threadIdx.x) * 8;
    f32x4 a = *(const f32x4*)(in + i);
    f32x4 b = *(const f32x4*)(in + i + 4);
    f16x8 o;
#pragma unroll
    for (int j = 0; j < 4; j++) { o[j] = (_Float16)a[j]; o[j + 4] = (_Float16)b[j]; }
    *(f16x8*)(out + i) = o;
}

// ---------------- Kernel 2: bidirectional LSTM scan via MFMA fp16, MG=4 replicated ----------------
// Grid = 128 blocks (2 dir x 64 batch-groups of 4), 512 threads = 8 waves.
// A rows = 4*batch + replica -> every lane owns all 4 gate-z of ONE cell.
__global__ void __launch_bounds__(512)
__attribute__((amdgpu_waves_per_eu(2, 2)))
scan_kernel(const _Float16* __restrict__ gru16, const _Float16* __restrict__ skips16,
            const float* __restrict__ maskt,
            const float* __restrict__ Kf, const float* __restrict__ Rf,
            const float* __restrict__ Skf, const float* __restrict__ bf,
            const float* __restrict__ Kb, const float* __restrict__ Rb,
            const float* __restrict__ Skb, const float* __restrict__ bb,
            _Float16* __restrict__ hs16, float* __restrict__ hfwd)
{
    __shared__ __align__(16) _Float16 h16[2 * MG * HP];

    const int tid = threadIdx.x;
    const int lane = tid & 63;
    const int w = tid >> 6;
    const int l16 = lane & 15;
    const int q = lane >> 4;         // this thread's batch row (0..3)
    const int mb = l16 >> 2;         // A-fragment source batch row (replicated)
    const int bg = blockIdx.x & 63;
    const int dir = blockIdx.x >> 6;
    const int b0 = bg * MG;
    const int col = 16 * w + l16;    // this thread's h column

    const float* Kw = dir ? Kb : Kf;
    const float* Rw = dir ? Rb : Rf;
    const float* Sw = dir ? Skb : Skf;
    const float* bw = dir ? bb : bf;

    // per-gate exp2 folding scale: sigmoid gates *log2e, tanh gate *2log2e
    const float gs[4] = {LOG2E, LOG2E, 2.0f * LOG2E, LOG2E};

    // B-fragments, gate-interleaved+scaled: bfr[kt][g][j] = gs[g]*W[32kt+8q+j][g*128+col]
    f16x8 bfr[7][4];
#pragma unroll
    for (int kt = 0; kt < 7; kt++) {
#pragma unroll
        for (int g = 0; g < 4; g++) {
            const int n = g * Hh + col;
            f16x8 v;
#pragma unroll
            for (int j = 0; j < 8; j++) {
                const int k = 32 * kt + 8 * q + j;
                float x;
                if (k < 32)        x = (k < Ee) ? Kw[k * H4n + n] : 0.0f;
                else if (k < 160)  x = Rw[(k - 32) * H4n + n];
                else               x = Sw[(k - 160) * H4n + n];
                v[j] = (_Float16)(x * gs[g]);
            }
            bfr[kt][g] = v;
        }
    }
    float biasv[4];
#pragma unroll
    for (int g = 0; g < 4; g++) biasv[g] = bw[g * Hh + col] * gs[g];

    for (int idx = tid; idx < 2 * MG * HP; idx += 512) h16[idx] = (_Float16)0.0f;

    const _Float16* srow = skips16 + (size_t)(b0 + mb) * Ss * SKIPn;
    float c = 0.0f, h = 0.0f;

    // hs16 write pointer; per-step delta +-256 halves
    _Float16* hsp = hs16 + ((size_t)(b0 + q) * Ss + (dir ? Ss - 1 : 0)) * (2 * Hh)
                    + dir * Hh + col;
    const ptrdiff_t odelta = dir ? -(2 * Hh) : (2 * Hh);

    auto issue_xs = [&](f16x8& xf, f16x8& s0, f16x8& s1, int i) {
        const int ii = (i < Ss) ? i : (Ss - 1);
        const int t = dir ? (Ss - 1 - ii) : ii;
        xf = *(const f16x8*)(gru16 + ((size_t)t * Bb + b0 + mb) * 32 + 8 * q);
        const _Float16* sp = srow + (size_t)t * SKIPn;
        s0 = *(const f16x8*)(sp + 8 * q);
        s1 = *(const f16x8*)(sp + 32 + 8 * q);
    };
    auto issue_m = [&](float& mk, int i) {
        const int ii = (i < Ss) ? i : (Ss - 1);
        const int t = dir ? (Ss - 1 - ii) : ii;
        mk = maskt[(size_t)t * Bb + b0 + q];
    };

    // 2-slot depth-2 prefetch
    f16x8 xA, xB, sA0, sA1, sB0, sB1;
    float mA, mB;
    issue_xs(xA, sA0, sA1, 0); issue_m(mA, 0);
    issue_xs(xB, sB0, sB1, 1); issue_m(mB, 1);
    __syncthreads();

    auto body = [&](int i, f16x8& xf, f16x8& s0, f16x8& s1, float& mkv) {
        // h fragments first: ds latency hides under the x/s MFMAs
        const _Float16* hb = h16 + (i & 1) * (MG * HP);
        const f16x8 ah0 = *(const f16x8*)(hb + mb * HP +  0 + 8 * q);
        const f16x8 ah1 = *(const f16x8*)(hb + mb * HP + 32 + 8 * q);
        const f16x8 ah2 = *(const f16x8*)(hb + mb * HP + 64 + 8 * q);
        const f16x8 ah3 = *(const f16x8*)(hb + mb * HP + 96 + 8 * q);

        f32x4 acc[4];
#pragma unroll
        for (int g = 0; g < 4; g++) {
            f32x4 a = {biasv[g], biasv[g], biasv[g], biasv[g]};
            acc[g] = a;
        }
#pragma unroll
        for (int g = 0; g < 4; g++) {
            acc[g] = __builtin_amdgcn_mfma_f32_16x16x32_f16(xf, bfr[0][g], acc[g], 0, 0, 0);
            acc[g] = __builtin_amdgcn_mfma_f32_16x16x32_f16(s0, bfr[5][g], acc[g], 0, 0, 0);
            acc[g] = __builtin_amdgcn_mfma_f32_16x16x32_f16(s1, bfr[6][g], acc[g], 0, 0, 0);
        }
        // refill x/s for step i+2 AFTER their last use (no fragment copies)
        issue_xs(xf, s0, s1, i + 2);
#pragma unroll
        for (int g = 0; g < 4; g++) {
            acc[g] = __builtin_amdgcn_mfma_f32_16x16x32_f16(ah0, bfr[1][g], acc[g], 0, 0, 0);
            acc[g] = __builtin_amdgcn_mfma_f32_16x16x32_f16(ah1, bfr[2][g], acc[g], 0, 0, 0);
            acc[g] = __builtin_amdgcn_mfma_f32_16x16x32_f16(ah2, bfr[3][g], acc[g], 0, 0, 0);
            acc[g] = __builtin_amdgcn_mfma_f32_16x16x32_f16(ah3, bfr[4][g], acc[g], 0, 0, 0);
        }

        // ---- gates: 1 cell/thread (batch q, col)
        const float mk = mkv;
        issue_m(mkv, i + 2);
        const float zi = acc[0][0], zf = acc[1][0], zg = acc[2][0], zo = acc[3][0];
        const float ei = exp2f_(fminf(-zi, 88.0f));   // e^{-z_i}
        const float ef = exp2f_(fminf(-zf, 88.0f));
        const float eg = exp2f_(fminf(-zg, 88.0f));   // e^{-2 z_g}
        const float eo = exp2f_(fminf(-zo, 88.0f));
        const float pi = 1.0f + ei, pg = 1.0f + eg, pf = 1.0f + ef;
        const float p  = pi * pg;
        const float t1 = (1.0f - eg) * pf;
        const float cn = fmaf(c, p, t1) * rcpf(pf * p);
        const float ec = exp2f_(fminf(cn * (-2.0f * LOG2E), 88.0f));   // e^{-2 cn}
        const float hn = (1.0f - ec) * rcpf((1.0f + eo) * (1.0f + ec));
        const bool mm = (mk != 0.0f);
        c = mm ? cn : c;
        h = mm ? hn : h;

        _Float16* hw = h16 + ((i + 1) & 1) * (MG * HP);
        hw[q * HP + col] = (_Float16)h;
        *hsp = (_Float16)h;
        hsp += odelta;
        lgkm_barrier();
    };

#pragma unroll 1
    for (int i = 0; i < Ss; i += 2) {
        body(i,     xA, sA0, sA1, mA);
        body(i + 1, xB, sB0, sB1, mB);
    }

    if (dir == 0) hfwd[(size_t)(b0 + q) * Hh + col] = h;
}

// ---------------- Kernel 3: fused attention: q + energy + softmax + context ----------------
// Grid = 256 blocks (1 per batch), 512 threads = 8 waves.
__global__ void __launch_bounds__(512)
attn_kernel(const _Float16* __restrict__ hs16, const float* __restrict__ hfwd,
            const float* __restrict__ Wq, const float* __restrict__ bq,
            const float* __restrict__ bk,
            const float* __restrict__ Wk, const float* __restrict__ We,
            const float* __restrict__ maskf, float* __restrict__ outp)
{
    __shared__ float hfl[Hh];
    __shared__ float qpart[4][Hh];
    __shared__ float qtot_s[Hh];
    __shared__ float epart[8][Ss];      // [wave][s] transposed: conflict-free
    __shared__ float ws2[Ss];           // softmax weights, transposed (s&31)*16+(s>>5)
    __shared__ float redm[8], reds[8];
    __shared__ float ctxp[16][2 * Hh + 1];  // pitch 257: ~2-way max

    const int tid = threadIdx.x;
    const int lane = tid & 63;
    const int w = tid >> 6;
    const int l16 = lane & 15;
    const int q = lane >> 4;
    const int b = blockIdx.x;
    const int j = 16 * w + l16;         // this wave's j-column (0..127)

    // Wk B-fragments (K = 2*Hh = 256): bk16[kt][jj] = Wk[32kt+8q+jj][j]
    f16x8 bk16[8];
#pragma unroll
    for (int kt = 0; kt < 8; kt++) {
        f16x8 v;
#pragma unroll
        for (int jj = 0; jj < 8; jj++)
            v[jj] = (_Float16)Wk[(32 * kt + 8 * q + jj) * Hh + j];
        bk16[kt] = v;
    }
    const float wej = We[j];

    // ---- phase 0: qtot = hfwd[b] @ Wq + bq + bk
    if (tid < Hh) hfl[tid] = hfwd[(size_t)b * Hh + tid];
    __syncthreads();
    {
        const int jj = tid & 127, seg = tid >> 7;
        float p = 0.0f;
#pragma unroll
        for (int k = 0; k < 32; k++)
            p += hfl[32 * seg + k] * Wq[(32 * seg + k) * Hh + jj];
        qpart[seg][jj] = p;
    }
    __syncthreads();
    if (tid < Hh)
        qtot_s[tid] = qpart[0][tid] + qpart[1][tid] + qpart[2][tid] + qpart[3][tid]
                      + bq[tid] + bk[tid];
    __syncthreads();
    const float qj = qtot_s[j];

    // ---- phase 1: energy partials via MFMA (each wave: all 32 s-tiles, its 16 j)
    const _Float16* hb = hs16 + (size_t)b * Ss * (2 * Hh);
#pragma unroll 1
    for (int st = 0; st < 32; st++) {
        const int s0 = st * 16;
        const _Float16* arow = hb + (size_t)(s0 + l16) * (2 * Hh) + 8 * q;
        f32x4 acc = {0.f, 0.f, 0.f, 0.f};
#pragma unroll
        for (int kt = 0; kt < 8; kt++) {
            const f16x8 a = *(const f16x8*)(arow + 32 * kt);
            acc = __builtin_amdgcn_mfma_f32_16x16x32_f16(a, bk16[kt], acc, 0, 0, 0);
        }
        float vals[4];
#pragma unroll
        for (int r = 0; r < 4; r++) {
            const float x = acc[r] + qj;
            const float e = exp2f_(fminf(x * (-2.0f * LOG2E), 80.0f));
            vals[r] = (1.0f - e) * rcpf(1.0f + e) * wej;   // tanh(x)*We[j]
        }
#pragma unroll
        for (int m = 1; m < 16; m <<= 1) {
#pragma unroll
            for (int r = 0; r < 4; r++) vals[r] += __shfl_xor(vals[r], m);
        }
        if (l16 == 0) {
#pragma unroll
            for (int r = 0; r < 4; r++) epart[w][s0 + 4 * q + r] = vals[r];
        }
    }
    __syncthreads();

    // ---- phase 2: masked softmax over S (thread tid owns s=tid)
    {
        float e = 0.0f;
#pragma unroll
        for (int ww = 0; ww < 8; ww++) e += epart[ww][tid];
        e += (1.0f - maskf[(size_t)b * Ss + tid]) * -1e9f;
        float mx = e;
#pragma unroll
        for (int off = 32; off > 0; off >>= 1) mx = fmaxf(mx, __shfl_xor(mx, off));
        if (lane == 0) redm[w] = mx;
        __syncthreads();
        mx = redm[0];
#pragma unroll
        for (int ww = 1; ww < 8; ww++) mx = fmaxf(mx, redm[ww]);
        const float p = exp2f_((e - mx) * LOG2E);
        float sm = p;
#pragma unroll
        for (int off = 32; off > 0; off >>= 1) sm += __shfl_xor(sm, off);
        if (lane == 0) reds[w] = sm;
        __syncthreads();
        sm = reds[0] + reds[1] + reds[2] + reds[3] + reds[4] + reds[5] + reds[6] + reds[7];
        ws2[(tid & 31) * 16 + (tid >> 5)] = p * rcpf(sm);
    }
    __syncthreads();

    // ---- phase 3: context. thread = (colgrp cg = tid>>4: cols 8cg..8cg+7, seg = tid&15)
    {
        const int cg = tid >> 4;
        const int seg = tid & 15;
        float a[8];
#pragma unroll
        for (int jj = 0; jj < 8; jj++) a[jj] = 0.0f;
#pragma unroll 4
        for (int sg = 0; sg < 32; sg++) {
            const int s = seg * 32 + sg;
            const float wv = ws2[sg * 16 + seg];
            const f16x8 hv = *(const f16x8*)(hb + (size_t)s * (2 * Hh) + 8 * cg);
#pragma unroll
            for (int jj = 0; jj < 8; jj++) a[jj] = fmaf(wv, (float)hv[jj], a[jj]);
        }
#pragma unroll
        for (int jj = 0; jj < 8; jj++) ctxp[seg][8 * cg + jj] = a[jj];
    }
    __syncthreads();
    if (tid < 2 * Hh) {
        float s = 0.0f;
#pragma unroll
        for (int seg = 0; seg < 16; seg++) s += ctxp[seg][tid];
        outp[(size_t)b * (2 * Hh) + tid] = s;
    }
}

// ---------------- Launcher ----------------
extern "C" void kernel_launch(void* const* d_in, const int* in_sizes, int n_in,
                              void* d_out, int out_size, void* d_ws, size_t ws_size,
                              hipStream_t stream) {
    const int*   tags  = (const int*)d_in[0];
    const float* skips = (const float*)d_in[1];
    const float* table = (const float*)d_in[2];
    const float* Kf    = (const float*)d_in[3];
    const float* Rf    = (const float*)d_in[4];
    const float* Skf   = (const float*)d_in[5];
    const float* bf    = (const float*)d_in[6];
    const float* Kb    = (const float*)d_in[7];
    const float* Rb    = (const float*)d_in[8];
    const float* Skb   = (const float*)d_in[9];
    const float* bb    = (const float*)d_in[10];
    const float* Wk    = (const float*)d_in[11];
    const float* bk    = (const float*)d_in[12];
    const float* Wq    = (const float*)d_in[13];
    const float* bq    = (const float*)d_in[14];
    const float* We    = (const float*)d_in[15];

    char* ws = (char*)d_ws;
    _Float16* gru16   = (_Float16*)ws; ws += (size_t)BSn * 32 * 2;      // 8.4 MB
    _Float16* skips16 = (_Float16*)ws; ws += (size_t)BSn * SKIPn * 2;   // 16.8 MB
    float* maskf  = (float*)ws;  ws += (size_t)BSn * 4;                 // 0.5 MB  [b][t]
    float* maskt  = (float*)ws;  ws += (size_t)BSn * 4;                 // 0.5 MB  [t][b]
    _Float16* hs16 = (_Float16*)ws; ws += (size_t)BSn * 2 * Hh * 2;     // 67.1 MB
    float* hfwd   = (float*)ws;  ws += (size_t)Bb * Hh * 4;             // total ~94 MB

    pool_kernel<<<BSn / 8, 256, 0, stream>>>(tags, table, gru16, maskf, maskt);
    cvt_kernel<<<BSn * SKIPn / (256 * 8), 256, 0, stream>>>(skips, skips16);
    scan_kernel<<<128, 512, 0, stream>>>(gru16, skips16, maskt,
                                         Kf, Rf, Skf, bf,
                                         Kb, Rb, Skb, bb,
                                         hs16, hfwd);
    attn_kernel<<<Bb, 512, 0, stream>>>(hs16, hfwd, Wq, bq, bk, Wk, We, maskf,
                                        (float*)d_out);
}